// Round 3
// baseline (389.625 us; speedup 1.0000x reference)
//
#include <hip/hip_runtime.h>
#include <hip/hip_bf16.h>

#define HH 8
#define NNq 2048
#define EPSF 1e-5f
#define LOG2E 1.4426950408889634f

typedef __bf16 bf16x8 __attribute__((ext_vector_type(8)));
typedef float f32x4 __attribute__((ext_vector_type(4)));

__device__ __forceinline__ unsigned short f2bf(float f) {
  union { float f; unsigned int u; } a;
  a.f = f;
  unsigned int r = a.u + 0x7fffu + ((a.u >> 16) & 1u);
  return (unsigned short)(r >> 16);
}
__device__ __forceinline__ float bf2f(unsigned short u) {
  union { unsigned int u; float f; } a;
  a.u = ((unsigned int)u) << 16;
  return a.f;
}

// ---------------------------------------------------------------------------
// z fp32 -> bf16
// ---------------------------------------------------------------------------
__global__ __launch_bounds__(256) void convert_z(const float* __restrict__ z,
                                                 unsigned short* __restrict__ zb) {
  const int i = (blockIdx.x * 256 + threadIdx.x) * 8;
  const float4 a = *(const float4*)&z[i];
  const float4 b = *(const float4*)&z[i + 4];
  union { unsigned short us[8]; uint4 v; } o;
  o.us[0] = f2bf(a.x); o.us[1] = f2bf(a.y); o.us[2] = f2bf(a.z); o.us[3] = f2bf(a.w);
  o.us[4] = f2bf(b.x); o.us[5] = f2bf(b.y); o.us[6] = f2bf(b.z); o.us[7] = f2bf(b.w);
  *(uint4*)&zb[i] = o.v;
}

// ---------------------------------------------------------------------------
// W fp32 [512,512] -> Wt bf16 [n][k] transposed, 4 weights.
// ---------------------------------------------------------------------------
__global__ __launch_bounds__(256) void transw_kernel(
    const float* __restrict__ W0, const float* __restrict__ W1,
    const float* __restrict__ W2, const float* __restrict__ W3,
    unsigned short* __restrict__ Wt) {
  __shared__ float Tl[64][68];
  const float* W = (blockIdx.z == 0) ? W0 : (blockIdx.z == 1) ? W1
                   : (blockIdx.z == 2) ? W2 : W3;
  unsigned short* dst = Wt + (size_t)blockIdx.z * 262144;
  const int t = threadIdx.x;
  const int k0 = blockIdx.x * 64, n0 = blockIdx.y * 64;
#pragma unroll
  for (int i = 0; i < 4; ++i) {
    const int idx = t + 256 * i;
    const int row = idx >> 4, cq = (idx & 15) * 4;
    *(float4*)&Tl[row][cq] = *(const float4*)&W[(size_t)(k0 + row) * 512 + n0 + cq];
  }
  __syncthreads();
#pragma unroll
  for (int i = 0; i < 4; ++i) {
    const int idx = t + 256 * i;
    const int nr = idx >> 4, kq = (idx & 15) * 4;
    ushort4 o;
    o.x = f2bf(Tl[kq + 0][nr]);
    o.y = f2bf(Tl[kq + 1][nr]);
    o.z = f2bf(Tl[kq + 2][nr]);
    o.w = f2bf(Tl[kq + 3][nr]);
    *(ushort4*)&dst[(size_t)(n0 + nr) * 512 + k0 + kq] = o;
  }
}

// ---------------------------------------------------------------------------
// Fused QKV projection. grid (64 rowtiles, 8 heads, 3 outputs).
// z=0 -> Q [B,H,N,64]; z=1 -> K [B,H,N,64]; z=2 -> Vt [B,H,64,N].
// ---------------------------------------------------------------------------
__global__ __launch_bounds__(256) void gemm_qkv(
    const unsigned short* __restrict__ A, const unsigned short* __restrict__ Wt3,
    const float* __restrict__ bq, const float* __restrict__ bk,
    const float* __restrict__ bvv, unsigned short* __restrict__ Qb,
    unsigned short* __restrict__ Kb, unsigned short* __restrict__ Vtb) {
  __shared__ unsigned short T[64][72];
  const int which = blockIdx.z;
  const unsigned short* Wt = Wt3 + (size_t)which * 262144;
  const float* bias = (which == 0) ? bq : (which == 1) ? bk : bvv;

  const int t = threadIdx.x;
  const int w = t >> 6, lane = t & 63, ln = lane & 15, quad = lane >> 4;
  const int r0 = blockIdx.x * 64, c0 = blockIdx.y * 64;

  f32x4 acc[4];
#pragma unroll
  for (int nt = 0; nt < 4; ++nt) acc[nt] = (f32x4)(0.0f);

  const unsigned short* arow = A + (size_t)(r0 + w * 16 + ln) * 512;
#pragma unroll 4
  for (int k = 0; k < 512; k += 32) {
    const bf16x8 a = *(const bf16x8*)&arow[k + quad * 8];
#pragma unroll
    for (int nt = 0; nt < 4; ++nt) {
      const bf16x8 b =
          *(const bf16x8*)&Wt[(size_t)(c0 + nt * 16 + ln) * 512 + k + quad * 8];
      acc[nt] = __builtin_amdgcn_mfma_f32_16x16x32_bf16(a, b, acc[nt], 0, 0, 0);
    }
  }

  const int rowl = w * 16 + quad * 4;
  const int h = blockIdx.y;
  if (which < 2) {
    unsigned short* ou = (which == 0) ? Qb : Kb;
#pragma unroll
    for (int nt = 0; nt < 4; ++nt) {
      const int d = nt * 16 + ln;
      const float bv = bias[c0 + d];
#pragma unroll
      for (int r = 0; r < 4; ++r) {
        const int rg = r0 + rowl + r;
        const int b = rg >> 11, n = rg & 2047;
        ou[((size_t)(b * HH + h) * NNq + n) * 64 + d] = f2bf(acc[nt][r] + bv);
      }
    }
  } else {
    const int b = r0 >> 11, n0 = r0 & 2047;
#pragma unroll
    for (int nt = 0; nt < 4; ++nt) {
      const int d = nt * 16 + ln;
      const float bv = bias[c0 + d];
#pragma unroll
      for (int r = 0; r < 4; ++r) T[d][rowl + r] = f2bf(acc[nt][r] + bv);
    }
    __syncthreads();
#pragma unroll
    for (int i = 0; i < 2; ++i) {
      const int idx = t + 256 * i;
      const int d = idx >> 3, nq = (idx & 7) * 8;
      *(uint4*)&Vtb[((size_t)(b * HH + h) * 64 + d) * NNq + n0 + nq] =
          *(const uint4*)&T[d][nq];
    }
  }
}

// ---------------------------------------------------------------------------
// Out projection: out fp32 = attnb bf16 [4096,512] @ WoT + bo.
// 64x32 block tile, wave = 16 rows x 32 cols. grid (64,16) = 1024 blocks.
// ---------------------------------------------------------------------------
__global__ __launch_bounds__(256) void gemm_out(
    const unsigned short* __restrict__ A, const unsigned short* __restrict__ Wt,
    const float* __restrict__ bias, float* __restrict__ of) {
  const int t = threadIdx.x;
  const int w = t >> 6, lane = t & 63, ln = lane & 15, quad = lane >> 4;
  const int r0 = blockIdx.x * 64, c0 = blockIdx.y * 32;

  f32x4 acc[2];
#pragma unroll
  for (int nt = 0; nt < 2; ++nt) acc[nt] = (f32x4)(0.0f);

  const unsigned short* arow = A + (size_t)(r0 + w * 16 + ln) * 512;
#pragma unroll 4
  for (int k = 0; k < 512; k += 32) {
    const bf16x8 a = *(const bf16x8*)&arow[k + quad * 8];
#pragma unroll
    for (int nt = 0; nt < 2; ++nt) {
      const bf16x8 b =
          *(const bf16x8*)&Wt[(size_t)(c0 + nt * 16 + ln) * 512 + k + quad * 8];
      acc[nt] = __builtin_amdgcn_mfma_f32_16x16x32_bf16(a, b, acc[nt], 0, 0, 0);
    }
  }
#pragma unroll
  for (int nt = 0; nt < 2; ++nt) {
    const int d = c0 + nt * 16 + ln;
    const float bv = bias[d];
#pragma unroll
    for (int r = 0; r < 4; ++r)
      of[(size_t)(r0 + w * 16 + quad * 4 + r) * 512 + d] = acc[nt][r] + bv;
  }
}

// ---------------------------------------------------------------------------
// Per-row stats. c1 = (0.125+2*dInv)*log2e, dv = dInv*log2e, k2, q2,
// k2max[bh] via block-reduced atomicMax (float-as-uint, values >= 0).
// ---------------------------------------------------------------------------
__global__ __launch_bounds__(256) void stats_kernel(
    const unsigned short* __restrict__ Q, const unsigned short* __restrict__ K,
    float* __restrict__ c1a, float* __restrict__ dva, float* __restrict__ k2a,
    float* __restrict__ q2a, unsigned int* __restrict__ k2max) {
  __shared__ float blkmax[4];
  const int t = threadIdx.x;
  const int lane = t & 63;
  const int wid = t >> 6;
  const int row = blockIdx.x * 4 + wid;

  const float qv = bf2f(Q[(size_t)row * 64 + lane]);
  float s = qv;
#pragma unroll
  for (int off = 1; off < 64; off <<= 1) s += __shfl_xor(s, off, 64);
  const float mu = s * (1.0f / 64.0f);
  const float dq = qv - mu;
  float v2 = dq * dq;
#pragma unroll
  for (int off = 1; off < 64; off <<= 1) v2 += __shfl_xor(v2, off, 64);
  const float sigma = sqrtf(v2 * (1.0f / 64.0f) + EPSF);
  float as = fabsf(dq);
#pragma unroll
  for (int off = 1; off < 64; off <<= 1) as += __shfl_xor(as, off, 64);
  const float nf = as / (sigma + EPSF);
  const float dInv = 1.0f / (__expf(-nf) + 1.0f);
  const float q2 = v2 + 64.0f * mu * mu;

  const float kv = bf2f(K[(size_t)row * 64 + lane]);
  float k2 = kv * kv;
#pragma unroll
  for (int off = 1; off < 64; off <<= 1) k2 += __shfl_xor(k2, off, 64);

  if (lane == 0) {
    c1a[row] = (0.125f + 2.0f * dInv) * LOG2E;
    dva[row] = dInv * LOG2E;
    k2a[row] = k2;
    q2a[row] = q2;
    blkmax[wid] = k2;
  }
  __syncthreads();
  if (t == 0) {
    const float m =
        fmaxf(fmaxf(blkmax[0], blkmax[1]), fmaxf(blkmax[2], blkmax[3]));
    atomicMax(&k2max[row >> 11], __float_as_uint(m));
  }
}

// ---------------------------------------------------------------------------
// Flash attention, key-split across waves, fixed per-query softmax bound.
// Block = 16 queries x (h,b); wave w owns keys [w*512, w*512+512).
// logits(log2-domain) = c1*qk - dv*k2[m]; p = exp2(logit - Mq),
// Mq = c1*sqrt(q2*k2max) >= c1*qk >= logit. No in-loop reductions at all.
// End: L lane-reduce + cross-wave (O,L) sum via LDS.
// ---------------------------------------------------------------------------
__global__ __launch_bounds__(256, 5) void attn_kernel(
    const unsigned short* __restrict__ Qb, const unsigned short* __restrict__ Kb,
    const unsigned short* __restrict__ Vt, const float* __restrict__ c1a,
    const float* __restrict__ dva, const float* __restrict__ k2a,
    const float* __restrict__ q2a, const unsigned int* __restrict__ k2maxu,
    unsigned short* __restrict__ attnb) {
  __shared__ __align__(16) char smem[17664];
  __bf16 (*Ps)[72] = (__bf16(*)[72])smem;       // [64][72] during K loop
  float (*Osh)[68] = (float(*)[68])smem;        // [64][68] after barrier
  float* Lsh = (float*)(smem + 17408);          // [64]

  const int t = threadIdx.x;
  const int w = t >> 6, lane = t & 63, ln = lane & 15, quad = lane >> 4;
  const int qt = blockIdx.x, h = blockIdx.y, b = blockIdx.z;
  const int bh = b * HH + h;
  const size_t qkbase = (size_t)bh * NNq * 64;
  const size_t vtbase = (size_t)bh * 64 * NNq;
  const int rowbase = bh * NNq;
  const int q0 = qt * 16;

  // Q fragments (same 16 queries for all 4 waves).
  const int qrow = q0 + ln;
  const bf16x8 aq0 = *(const bf16x8*)&Qb[qkbase + (size_t)qrow * 64 + quad * 8];
  const bf16x8 aq1 = *(const bf16x8*)&Qb[qkbase + (size_t)qrow * 64 + 32 + quad * 8];

  const float k2m = __uint_as_float(k2maxu[bh]);

  float c1r[4], dvr[4], Mq[4];
#pragma unroll
  for (int r = 0; r < 4; ++r) {
    const int qr = q0 + quad * 4 + r;
    c1r[r] = c1a[rowbase + qr];
    dvr[r] = dva[rowbase + qr];
    Mq[r] = c1r[r] * sqrtf(q2a[rowbase + qr] * k2m);
  }

  float L[4] = {0.0f, 0.0f, 0.0f, 0.0f};
  f32x4 O[4];
#pragma unroll
  for (int nt = 0; nt < 4; ++nt) O[nt] = (f32x4)(0.0f);

  const int mbase = w * 512;
  for (int kt = 0; kt < 8; ++kt) {
    const int m0 = mbase + kt * 64;
    // ---- S = Q K^T ----
    f32x4 s[4];
#pragma unroll
    for (int nt = 0; nt < 4; ++nt) {
      const size_t kr = qkbase + (size_t)(m0 + nt * 16 + ln) * 64;
      const bf16x8 b0 = *(const bf16x8*)&Kb[kr + quad * 8];
      const bf16x8 b1 = *(const bf16x8*)&Kb[kr + 32 + quad * 8];
      f32x4 a = (f32x4)(0.0f);
      a = __builtin_amdgcn_mfma_f32_16x16x32_bf16(aq0, b0, a, 0, 0, 0);
      a = __builtin_amdgcn_mfma_f32_16x16x32_bf16(aq1, b1, a, 0, 0, 0);
      s[nt] = a;
    }
    float k2v[4];
#pragma unroll
    for (int nt = 0; nt < 4; ++nt) k2v[nt] = k2a[rowbase + m0 + nt * 16 + ln];

    // ---- p = exp2(logit - Mq); accumulate L; stage P in LDS (A-layout) ----
#pragma unroll
    for (int nt = 0; nt < 4; ++nt) {
#pragma unroll
      for (int r = 0; r < 4; ++r) {
        const float e = c1r[r] * s[nt][r] - dvr[r] * k2v[nt] - Mq[r];
        const float pv = __builtin_amdgcn_exp2f(e);
        L[r] += pv;
        Ps[w * 16 + quad * 4 + r][nt * 16 + ln] = (__bf16)pv;
      }
    }
    const bf16x8 pa0 = *(const bf16x8*)&Ps[w * 16 + ln][quad * 8];
    const bf16x8 pa1 = *(const bf16x8*)&Ps[w * 16 + ln][32 + quad * 8];

    // ---- O += P V ----
#pragma unroll
    for (int nt = 0; nt < 4; ++nt) {
      const size_t vr = vtbase + (size_t)(nt * 16 + ln) * NNq + m0;
      const bf16x8 vb0 = *(const bf16x8*)&Vt[vr + quad * 8];
      const bf16x8 vb1 = *(const bf16x8*)&Vt[vr + 32 + quad * 8];
      O[nt] = __builtin_amdgcn_mfma_f32_16x16x32_bf16(pa0, vb0, O[nt], 0, 0, 0);
      O[nt] = __builtin_amdgcn_mfma_f32_16x16x32_bf16(pa1, vb1, O[nt], 0, 0, 0);
    }
  }

  // ---- L: reduce across the 16 lanes sharing a query row ----
#pragma unroll
  for (int r = 0; r < 4; ++r) {
#pragma unroll
    for (int off = 1; off < 16; off <<= 1) L[r] += __shfl_xor(L[r], off, 64);
  }

  __syncthreads();  // Ps reads done; smem becomes Osh/Lsh
#pragma unroll
  for (int nt = 0; nt < 4; ++nt)
#pragma unroll
    for (int r = 0; r < 4; ++r)
      Osh[w * 16 + quad * 4 + r][nt * 16 + ln] = O[nt][r];
  if (ln == 0) {
#pragma unroll
    for (int r = 0; r < 4; ++r) Lsh[w * 16 + quad * 4 + r] = L[r];
  }
  __syncthreads();

  // ---- combine 4 key-quarters; write bf16 [B,N,DIM] ----
  const int q = t >> 4;
  const int d0 = (t & 15) * 4;
  float4 acc = {0.0f, 0.0f, 0.0f, 0.0f};
  float Lt = 0.0f;
#pragma unroll
  for (int w2 = 0; w2 < 4; ++w2) {
    const float4 o = *(const float4*)&Osh[w2 * 16 + q][d0];
    acc.x += o.x; acc.y += o.y; acc.z += o.z; acc.w += o.w;
    Lt += Lsh[w2 * 16 + q];
  }
  const float inv = 1.0f / Lt;
  ushort4 ov;
  ov.x = f2bf(acc.x * inv);
  ov.y = f2bf(acc.y * inv);
  ov.z = f2bf(acc.z * inv);
  ov.w = f2bf(acc.w * inv);
  *(ushort4*)&attnb[((size_t)(b * NNq + q0 + q)) * 512 + h * 64 + d0] = ov;
}

// ---------------------------------------------------------------------------
extern "C" void kernel_launch(void* const* d_in, const int* in_sizes, int n_in,
                              void* d_out, int out_size, void* d_ws,
                              size_t ws_size, hipStream_t stream) {
  const float* z = (const float*)d_in[0];
  const float* Wq = (const float*)d_in[1];
  const float* bq = (const float*)d_in[2];
  const float* Wk = (const float*)d_in[3];
  const float* bk = (const float*)d_in[4];
  const float* Wv = (const float*)d_in[5];
  const float* bv = (const float*)d_in[6];
  const float* Wo = (const float*)d_in[7];
  const float* bo = (const float*)d_in[8];
  float* out = (float*)d_out;

  char* ws = (char*)d_ws;
  unsigned short* zb = (unsigned short*)(ws);                // 4 MiB
  unsigned short* Wt = (unsigned short*)(ws + 4194304);      // 2 MiB
  unsigned short* Qb = (unsigned short*)(ws + 6291456);      // 4 MiB
  unsigned short* Kb = (unsigned short*)(ws + 10485760);     // 4 MiB
  unsigned short* Vtb = (unsigned short*)(ws + 14680064);    // 4 MiB
  float* c1 = (float*)(ws + 18874368);                       // 128 KiB each
  float* dv = (float*)(ws + 19005440);
  float* k2 = (float*)(ws + 19136512);
  float* q2 = (float*)(ws + 19267584);
  unsigned short* attnb = (unsigned short*)(ws + 19398656);  // 4 MiB
  unsigned int* k2max = (unsigned int*)(ws + 23592960);      // 64 B

  hipLaunchKernelGGL(convert_z, dim3(1024), dim3(256), 0, stream, z, zb);
  hipLaunchKernelGGL(transw_kernel, dim3(8, 8, 4), dim3(256), 0, stream,
                     Wq, Wk, Wv, Wo, Wt);
  hipMemsetAsync(k2max, 0, 64, stream);
  hipLaunchKernelGGL(gemm_qkv, dim3(64, 8, 3), dim3(256), 0, stream, zb, Wt,
                     bq, bk, bv, Qb, Kb, Vtb);
  hipLaunchKernelGGL(stats_kernel, dim3(8192), dim3(256), 0, stream, Qb, Kb,
                     c1, dv, k2, q2, k2max);
  hipLaunchKernelGGL(attn_kernel, dim3(128, 8, 2), dim3(256), 0, stream, Qb,
                     Kb, Vtb, c1, dv, k2, q2, k2max, attnb);
  hipLaunchKernelGGL(gemm_out, dim3(64, 16), dim3(256), 0, stream, attnb, Wt + 786432,
                     bo, out);
}

// Round 4
// 200.093 us; speedup vs baseline: 1.9472x; 1.9472x over previous
//
#include <hip/hip_runtime.h>
#include <hip/hip_bf16.h>

#define HH 8
#define NNq 2048
#define EPSF 1e-5f
#define LOG2E 1.4426950408889634f

typedef __bf16 bf16x8 __attribute__((ext_vector_type(8)));
typedef float f32x4 __attribute__((ext_vector_type(4)));

typedef const __attribute__((address_space(1))) unsigned int* gas_t;
typedef __attribute__((address_space(3))) unsigned int* las_t;

__device__ __forceinline__ void async16(const void* g, void* l) {
  __builtin_amdgcn_global_load_lds((gas_t)g, (las_t)l, 16, 0, 0);
}
__device__ __forceinline__ void async4(const void* g, void* l) {
  __builtin_amdgcn_global_load_lds((gas_t)g, (las_t)l, 4, 0, 0);
}

__device__ __forceinline__ unsigned short f2bf(float f) {
  union { float f; unsigned int u; } a;
  a.f = f;
  unsigned int r = a.u + 0x7fffu + ((a.u >> 16) & 1u);
  return (unsigned short)(r >> 16);
}

// ---------------------------------------------------------------------------
// z fp32 -> bf16
// ---------------------------------------------------------------------------
__global__ __launch_bounds__(256) void convert_z(const float* __restrict__ z,
                                                 unsigned short* __restrict__ zb) {
  const int i = (blockIdx.x * 256 + threadIdx.x) * 8;
  const float4 a = *(const float4*)&z[i];
  const float4 b = *(const float4*)&z[i + 4];
  union { unsigned short us[8]; uint4 v; } o;
  o.us[0] = f2bf(a.x); o.us[1] = f2bf(a.y); o.us[2] = f2bf(a.z); o.us[3] = f2bf(a.w);
  o.us[4] = f2bf(b.x); o.us[5] = f2bf(b.y); o.us[6] = f2bf(b.z); o.us[7] = f2bf(b.w);
  *(uint4*)&zb[i] = o.v;
}

// ---------------------------------------------------------------------------
// W fp32 [512,512] -> Wt bf16 [n][k] transposed, 4 weights.
// ---------------------------------------------------------------------------
__global__ __launch_bounds__(256) void transw_kernel(
    const float* __restrict__ W0, const float* __restrict__ W1,
    const float* __restrict__ W2, const float* __restrict__ W3,
    unsigned short* __restrict__ Wt) {
  __shared__ float Tl[64][68];
  const float* W = (blockIdx.z == 0) ? W0 : (blockIdx.z == 1) ? W1
                   : (blockIdx.z == 2) ? W2 : W3;
  unsigned short* dst = Wt + (size_t)blockIdx.z * 262144;
  const int t = threadIdx.x;
  const int k0 = blockIdx.x * 64, n0 = blockIdx.y * 64;
#pragma unroll
  for (int i = 0; i < 4; ++i) {
    const int idx = t + 256 * i;
    const int row = idx >> 4, cq = (idx & 15) * 4;
    *(float4*)&Tl[row][cq] = *(const float4*)&W[(size_t)(k0 + row) * 512 + n0 + cq];
  }
  __syncthreads();
#pragma unroll
  for (int i = 0; i < 4; ++i) {
    const int idx = t + 256 * i;
    const int nr = idx >> 4, kq = (idx & 15) * 4;
    ushort4 o;
    o.x = f2bf(Tl[kq + 0][nr]);
    o.y = f2bf(Tl[kq + 1][nr]);
    o.z = f2bf(Tl[kq + 2][nr]);
    o.w = f2bf(Tl[kq + 3][nr]);
    *(ushort4*)&dst[(size_t)(n0 + nr) * 512 + k0 + kq] = o;
  }
}

// ---------------------------------------------------------------------------
// Fused QKV projection + stats. grid (64 rowtiles, 8 heads, 3 modes).
// mode 0: Q bf16 [bh][n][64] + per-row c1/dv/q2 stats (fp32 C-regs).
// mode 1: K swizzled tiles [bh][kt][8KB] + k2 per row + k2max[bh] atomic.
// mode 2: V swizzled tiles (rows=dim, cols=key) [bh][kt][8KB].
// Tile swizzle: off_us(row,d) = row*64 + ((d>>3 ^ (row&7))*8) + (d&7).
// ---------------------------------------------------------------------------
__global__ __launch_bounds__(256) void gemm_qkv(
    const unsigned short* __restrict__ A, const unsigned short* __restrict__ Wt3,
    const float* __restrict__ bq, const float* __restrict__ bk,
    const float* __restrict__ bvv, unsigned short* __restrict__ Qb,
    unsigned short* __restrict__ Ksw, unsigned short* __restrict__ Vsw,
    float* __restrict__ c1a, float* __restrict__ dva, float* __restrict__ k2a,
    float* __restrict__ q2a, unsigned int* __restrict__ k2max) {
  __shared__ unsigned short T[64 * 72];  // mode 0 staging (padded) / modes 1,2 use first 4096
  __shared__ float wmax[4];

  const int which = blockIdx.z;
  const unsigned short* Wt = Wt3 + (size_t)which * 262144;
  const float* bias = (which == 0) ? bq : (which == 1) ? bk : bvv;

  const int t = threadIdx.x;
  const int w = t >> 6, lane = t & 63, ln = lane & 15, quad = lane >> 4;
  const int r0 = blockIdx.x * 64, h = blockIdx.y;
  const int c0 = h * 64;
  const int b = r0 >> 11, n0 = r0 & 2047;
  const int bh = b * HH + h;

  f32x4 acc[4];
#pragma unroll
  for (int nt = 0; nt < 4; ++nt) acc[nt] = (f32x4)(0.0f);

  const unsigned short* arow = A + (size_t)(r0 + w * 16 + ln) * 512;
#pragma unroll 4
  for (int k = 0; k < 512; k += 32) {
    const bf16x8 a = *(const bf16x8*)&arow[k + quad * 8];
#pragma unroll
    for (int nt = 0; nt < 4; ++nt) {
      const bf16x8 bb =
          *(const bf16x8*)&Wt[(size_t)(c0 + nt * 16 + ln) * 512 + k + quad * 8];
      acc[nt] = __builtin_amdgcn_mfma_f32_16x16x32_bf16(a, bb, acc[nt], 0, 0, 0);
    }
  }

  // add bias into regs
  float x[4][4];  // [nt][r]
#pragma unroll
  for (int nt = 0; nt < 4; ++nt) {
    const float bv = bias[c0 + nt * 16 + ln];
#pragma unroll
    for (int r = 0; r < 4; ++r) x[nt][r] = acc[nt][r] + bv;
  }
  const int rowl = w * 16 + quad * 4;  // +r

  if (which == 0) {
    // ---- per-row stats from fp32 regs (16 lanes quad-group hold one row) ----
#pragma unroll
    for (int r = 0; r < 4; ++r) {
      float s1 = x[0][r] + x[1][r] + x[2][r] + x[3][r];
#pragma unroll
      for (int off = 1; off < 16; off <<= 1) s1 += __shfl_xor(s1, off, 64);
      const float mu = s1 * (1.0f / 64.0f);
      float s2 = 0.0f, sa = 0.0f;
#pragma unroll
      for (int nt = 0; nt < 4; ++nt) {
        const float dx = x[nt][r] - mu;
        s2 += dx * dx;
        sa += fabsf(dx);
      }
#pragma unroll
      for (int off = 1; off < 16; off <<= 1) {
        s2 += __shfl_xor(s2, off, 64);
        sa += __shfl_xor(sa, off, 64);
      }
      if (ln == 0) {
        const float sigma = sqrtf(s2 * (1.0f / 64.0f) + EPSF);
        const float nf = sa / (sigma + EPSF);
        const float dInv = 1.0f / (__expf(-nf) + 1.0f);
        const int row = bh * NNq + n0 + rowl + r;
        c1a[row] = (0.125f + 2.0f * dInv) * LOG2E;
        dva[row] = dInv * LOG2E;
        q2a[row] = s2 + 64.0f * mu * mu;
      }
    }
    // ---- stage bf16 Q and store coalesced [bh][n][64] ----
#pragma unroll
    for (int nt = 0; nt < 4; ++nt)
#pragma unroll
      for (int r = 0; r < 4; ++r)
        T[(rowl + r) * 72 + nt * 16 + ln] = f2bf(x[nt][r]);
    __syncthreads();
#pragma unroll
    for (int i = 0; i < 2; ++i) {
      const int idx = t + 256 * i;
      const int q = idx >> 3, c = idx & 7;
      *(uint4*)&Qb[((size_t)bh * NNq + n0 + q) * 64 + c * 8] =
          *(const uint4*)&T[q * 72 + c * 8];
    }
  } else if (which == 1) {
    // ---- k2 per row + block max ----
    float mx = 0.0f;
#pragma unroll
    for (int r = 0; r < 4; ++r) {
      float s2 = x[0][r] * x[0][r] + x[1][r] * x[1][r] + x[2][r] * x[2][r] +
                 x[3][r] * x[3][r];
#pragma unroll
      for (int off = 1; off < 16; off <<= 1) s2 += __shfl_xor(s2, off, 64);
      if (ln == 0) k2a[bh * NNq + n0 + rowl + r] = s2;
      mx = fmaxf(mx, s2);
    }
#pragma unroll
    for (int off = 16; off < 64; off <<= 1) mx = fmaxf(mx, __shfl_xor(mx, off, 64));
    if (lane == 0) wmax[w] = mx;
    // ---- stage swizzled K tile image ----
#pragma unroll
    for (int nt = 0; nt < 4; ++nt) {
      const int d = nt * 16 + ln, c = nt * 2 + (ln >> 3);
#pragma unroll
      for (int r = 0; r < 4; ++r) {
        const int key = rowl + r;
        T[key * 64 + ((c ^ (key & 7)) * 8) + (ln & 7)] = f2bf(x[nt][r]);
      }
    }
    __syncthreads();
    if (t == 0) {
      const float m = fmaxf(fmaxf(wmax[0], wmax[1]), fmaxf(wmax[2], wmax[3]));
      atomicMax(&k2max[bh * 16], __float_as_uint(m));
    }
    unsigned short* dst = Ksw + ((size_t)bh * 32 + (n0 >> 6)) * 4096;
#pragma unroll
    for (int i = 0; i < 2; ++i) {
      const int idx = t + 256 * i;
      *(uint4*)&dst[idx * 8] = *(const uint4*)&T[idx * 8];
    }
  } else {
    // ---- stage swizzled V tile image (rows = dim, cols = key) ----
#pragma unroll
    for (int nt = 0; nt < 4; ++nt) {
      const int d = nt * 16 + ln;
#pragma unroll
      for (int r = 0; r < 4; ++r) {
        const int key = rowl + r;
        T[d * 64 + (((key >> 3) ^ (d & 7)) * 8) + (key & 7)] = f2bf(x[nt][r]);
      }
    }
    __syncthreads();
    unsigned short* dst = Vsw + ((size_t)bh * 32 + (n0 >> 6)) * 4096;
#pragma unroll
    for (int i = 0; i < 2; ++i) {
      const int idx = t + 256 * i;
      *(uint4*)&dst[idx * 8] = *(const uint4*)&T[idx * 8];
    }
  }
}

// ---------------------------------------------------------------------------
// Flash attention: block = 64 queries x bh, 4 waves (16 q each, full keys).
// K/V staged via global_load_lds from pre-swizzled tiles; fixed-bound softmax.
// ---------------------------------------------------------------------------
__global__ __launch_bounds__(256) void attn_kernel(
    const unsigned short* __restrict__ Qb, const unsigned short* __restrict__ Ksw,
    const unsigned short* __restrict__ Vsw, const float* __restrict__ c1a,
    const float* __restrict__ dva, const float* __restrict__ k2a,
    const float* __restrict__ q2a, const unsigned int* __restrict__ k2maxu,
    unsigned short* __restrict__ attnb) {
  __shared__ __align__(16) unsigned short Kt[4096];
  __shared__ __align__(16) unsigned short Vt[4096];
  __shared__ __align__(16) unsigned short Ps[64 * 72];
  __shared__ __align__(16) float k2t[64];

  const int t = threadIdx.x;
  const int w = t >> 6, lane = t & 63, ln = lane & 15, quad = lane >> 4;
  const int qt = blockIdx.x, bh = blockIdx.y;
  const int b = bh >> 3, h = bh & 7;
  const int q0 = qt * 64;
  const int rowbase = bh * NNq;

  const unsigned short* qrow = Qb + ((size_t)rowbase + q0 + w * 16 + ln) * 64;
  const bf16x8 aq0 = *(const bf16x8*)(qrow + quad * 8);
  const bf16x8 aq1 = *(const bf16x8*)(qrow + 32 + quad * 8);

  const float k2m = __uint_as_float(k2maxu[bh * 16]);
  float c1r[4], dvr[4], Mq[4], L[4] = {0.0f, 0.0f, 0.0f, 0.0f};
  f32x4 O[4];
#pragma unroll
  for (int nt = 0; nt < 4; ++nt) O[nt] = (f32x4)(0.0f);
#pragma unroll
  for (int r = 0; r < 4; ++r) {
    const int qr = q0 + w * 16 + quad * 4 + r;
    c1r[r] = c1a[rowbase + qr];
    dvr[r] = dva[rowbase + qr];
    Mq[r] = c1r[r] * sqrtf(q2a[rowbase + qr] * k2m);
  }

  const unsigned short* Kg = Ksw + (size_t)bh * 32 * 4096;
  const unsigned short* Vg = Vsw + (size_t)bh * 32 * 4096;
  const float* k2g = k2a + rowbase;
  const int sw = quad ^ (ln & 7);        // swizzled chunk for b0
  const int sw1 = (4 + quad) ^ (ln & 7); // swizzled chunk for b1

  for (int kt = 0; kt < 32; ++kt) {
    // ---- cooperative stage of K/V tiles (+k2 row) ----
    {
      const size_t tb = (size_t)kt * 4096 + w * 1024;
      async16(Kg + tb + lane * 8, Kt + w * 1024);
      async16(Kg + tb + 512 + lane * 8, Kt + w * 1024 + 512);
      async16(Vg + tb + lane * 8, Vt + w * 1024);
      async16(Vg + tb + 512 + lane * 8, Vt + w * 1024 + 512);
      if (w == 0) async4(k2g + kt * 64 + lane, k2t);
    }
    __syncthreads();

    // ---- S = Q K^T ----
    f32x4 s[4];
#pragma unroll
    for (int nt = 0; nt < 4; ++nt) {
      const unsigned short* kb = Kt + (nt * 16 + ln) * 64;
      const bf16x8 b0 = *(const bf16x8*)(kb + sw * 8);
      const bf16x8 b1 = *(const bf16x8*)(kb + sw1 * 8);
      f32x4 a = (f32x4)(0.0f);
      a = __builtin_amdgcn_mfma_f32_16x16x32_bf16(aq0, b0, a, 0, 0, 0);
      a = __builtin_amdgcn_mfma_f32_16x16x32_bf16(aq1, b1, a, 0, 0, 0);
      s[nt] = a;
    }

    // ---- p = exp2(logit - Mq); L accumulate; P -> LDS (A-layout) ----
    float k2v[4];
#pragma unroll
    for (int nt = 0; nt < 4; ++nt) k2v[nt] = k2t[nt * 16 + ln];
#pragma unroll
    for (int nt = 0; nt < 4; ++nt) {
#pragma unroll
      for (int r = 0; r < 4; ++r) {
        const float e = c1r[r] * s[nt][r] - dvr[r] * k2v[nt] - Mq[r];
        const float pv = __builtin_amdgcn_exp2f(e);
        L[r] += pv;
        Ps[(w * 16 + quad * 4 + r) * 72 + nt * 16 + ln] = f2bf(pv);
      }
    }
    const unsigned short* pr = Ps + (w * 16 + ln) * 72;
    const bf16x8 pa0 = *(const bf16x8*)(pr + quad * 8);
    const bf16x8 pa1 = *(const bf16x8*)(pr + 32 + quad * 8);

    // ---- O += P V ----
#pragma unroll
    for (int nt = 0; nt < 4; ++nt) {
      const unsigned short* vb = Vt + (nt * 16 + ln) * 64;
      const bf16x8 vb0 = *(const bf16x8*)(vb + sw * 8);
      const bf16x8 vb1 = *(const bf16x8*)(vb + sw1 * 8);
      O[nt] = __builtin_amdgcn_mfma_f32_16x16x32_bf16(pa0, vb0, O[nt], 0, 0, 0);
      O[nt] = __builtin_amdgcn_mfma_f32_16x16x32_bf16(pa1, vb1, O[nt], 0, 0, 0);
    }
    __syncthreads();  // all LDS reads done before next stage overwrites
  }

  // ---- finalize: L reduce over 16 lanes; write via LDS for 16B stores ----
  float inv[4];
#pragma unroll
  for (int r = 0; r < 4; ++r) {
#pragma unroll
    for (int off = 1; off < 16; off <<= 1) L[r] += __shfl_xor(L[r], off, 64);
    inv[r] = 1.0f / L[r];
  }
#pragma unroll
  for (int nt = 0; nt < 4; ++nt)
#pragma unroll
    for (int r = 0; r < 4; ++r)
      Ps[(w * 16 + quad * 4 + r) * 72 + nt * 16 + ln] = f2bf(O[nt][r] * inv[r]);
  __syncthreads();
#pragma unroll
  for (int i = 0; i < 2; ++i) {
    const int idx = t + 256 * i;
    const int q = idx >> 3, c = idx & 7;
    *(uint4*)&attnb[((size_t)(b * NNq + q0 + q)) * 512 + h * 64 + c * 8] =
        *(const uint4*)&Ps[q * 72 + c * 8];
  }
}

// ---------------------------------------------------------------------------
// Out projection: out fp32 = attnb bf16 [4096,512] @ WoT + bo. 64x64 tiles.
// ---------------------------------------------------------------------------
__global__ __launch_bounds__(256) void gemm_out(
    const unsigned short* __restrict__ A, const unsigned short* __restrict__ Wt,
    const float* __restrict__ bias, float* __restrict__ of) {
  __shared__ float Tl[64][68];
  const int t = threadIdx.x;
  const int w = t >> 6, lane = t & 63, ln = lane & 15, quad = lane >> 4;
  const int r0 = blockIdx.x * 64, c0 = blockIdx.y * 64;

  f32x4 acc[4];
#pragma unroll
  for (int nt = 0; nt < 4; ++nt) acc[nt] = (f32x4)(0.0f);

  const unsigned short* arow = A + (size_t)(r0 + w * 16 + ln) * 512;
#pragma unroll 4
  for (int k = 0; k < 512; k += 32) {
    const bf16x8 a = *(const bf16x8*)&arow[k + quad * 8];
#pragma unroll
    for (int nt = 0; nt < 4; ++nt) {
      const bf16x8 bb =
          *(const bf16x8*)&Wt[(size_t)(c0 + nt * 16 + ln) * 512 + k + quad * 8];
      acc[nt] = __builtin_amdgcn_mfma_f32_16x16x32_bf16(a, bb, acc[nt], 0, 0, 0);
    }
  }
#pragma unroll
  for (int nt = 0; nt < 4; ++nt) {
    const float bv = bias[c0 + nt * 16 + ln];
#pragma unroll
    for (int r = 0; r < 4; ++r)
      Tl[w * 16 + quad * 4 + r][nt * 16 + ln] = acc[nt][r] + bv;
  }
  __syncthreads();
#pragma unroll
  for (int i = 0; i < 4; ++i) {
    const int idx = t + 256 * i;
    const int row = idx >> 4, c4 = (idx & 15) * 4;
    *(float4*)&of[(size_t)(r0 + row) * 512 + c0 + c4] = *(const float4*)&Tl[row][c4];
  }
}

// ---------------------------------------------------------------------------
extern "C" void kernel_launch(void* const* d_in, const int* in_sizes, int n_in,
                              void* d_out, int out_size, void* d_ws,
                              size_t ws_size, hipStream_t stream) {
  const float* z = (const float*)d_in[0];
  const float* Wq = (const float*)d_in[1];
  const float* bq = (const float*)d_in[2];
  const float* Wk = (const float*)d_in[3];
  const float* bk = (const float*)d_in[4];
  const float* Wv = (const float*)d_in[5];
  const float* bv = (const float*)d_in[6];
  const float* Wo = (const float*)d_in[7];
  const float* bo = (const float*)d_in[8];
  float* out = (float*)d_out;

  char* ws = (char*)d_ws;
  unsigned short* zb = (unsigned short*)(ws);                // 4 MiB
  unsigned short* Wt = (unsigned short*)(ws + 4194304);      // 2 MiB
  unsigned short* Qb = (unsigned short*)(ws + 6291456);      // 4 MiB
  unsigned short* Ksw = (unsigned short*)(ws + 10485760);    // 4 MiB (swizzled tiles)
  unsigned short* Vsw = (unsigned short*)(ws + 14680064);    // 4 MiB (swizzled tiles)
  float* c1 = (float*)(ws + 18874368);                       // 128 KiB each
  float* dv = (float*)(ws + 19005440);
  float* k2 = (float*)(ws + 19136512);
  float* q2 = (float*)(ws + 19267584);
  unsigned short* attnb = (unsigned short*)(ws + 19398656);  // 4 MiB
  unsigned int* k2max = (unsigned int*)(ws + 23592960);      // 1 KiB (16 x 64B)

  hipLaunchKernelGGL(convert_z, dim3(1024), dim3(256), 0, stream, z, zb);
  hipLaunchKernelGGL(transw_kernel, dim3(8, 8, 4), dim3(256), 0, stream,
                     Wq, Wk, Wv, Wo, Wt);
  hipMemsetAsync(k2max, 0, 1024, stream);
  hipLaunchKernelGGL(gemm_qkv, dim3(64, 8, 3), dim3(256), 0, stream, zb, Wt,
                     bq, bk, bv, Qb, Ksw, Vsw, c1, dv, k2, q2, k2max);
  hipLaunchKernelGGL(attn_kernel, dim3(32, 16), dim3(256), 0, stream, Qb, Ksw,
                     Vsw, c1, dv, k2, q2, k2max, attnb);
  hipLaunchKernelGGL(gemm_out, dim3(64, 8), dim3(256), 0, stream, attnb,
                     Wt + 786432, bo, out);
}

// Round 5
// 148.703 us; speedup vs baseline: 2.6202x; 1.3456x over previous
//
#include <hip/hip_runtime.h>
#include <hip/hip_bf16.h>

#define HH 8
#define NNq 2048
#define EPSF 1e-5f
#define LOG2E 1.4426950408889634f

typedef __bf16 bf16x8 __attribute__((ext_vector_type(8)));
typedef float f32x4 __attribute__((ext_vector_type(4)));

typedef const __attribute__((address_space(1))) unsigned int* gas_t;
typedef __attribute__((address_space(3))) unsigned int* las_t;

__device__ __forceinline__ void async16(const void* g, void* l) {
  __builtin_amdgcn_global_load_lds((gas_t)g, (las_t)l, 16, 0, 0);
}
__device__ __forceinline__ void async4(const void* g, void* l) {
  __builtin_amdgcn_global_load_lds((gas_t)g, (las_t)l, 4, 0, 0);
}

__device__ __forceinline__ unsigned short f2bf(float f) {
  union { float f; unsigned int u; } a;
  a.f = f;
  unsigned int r = a.u + 0x7fffu + ((a.u >> 16) & 1u);
  return (unsigned short)(r >> 16);
}

// ---------------------------------------------------------------------------
// z fp32 -> bf16
// ---------------------------------------------------------------------------
__global__ __launch_bounds__(256) void convert_z(const float* __restrict__ z,
                                                 unsigned short* __restrict__ zb) {
  const int i = (blockIdx.x * 256 + threadIdx.x) * 8;
  const float4 a = *(const float4*)&z[i];
  const float4 b = *(const float4*)&z[i + 4];
  union { unsigned short us[8]; uint4 v; } o;
  o.us[0] = f2bf(a.x); o.us[1] = f2bf(a.y); o.us[2] = f2bf(a.z); o.us[3] = f2bf(a.w);
  o.us[4] = f2bf(b.x); o.us[5] = f2bf(b.y); o.us[6] = f2bf(b.z); o.us[7] = f2bf(b.w);
  *(uint4*)&zb[i] = o.v;
}

// ---------------------------------------------------------------------------
// W fp32 [512,512] -> Wt bf16 [n][k] transposed, 4 weights.
// ---------------------------------------------------------------------------
__global__ __launch_bounds__(256) void transw_kernel(
    const float* __restrict__ W0, const float* __restrict__ W1,
    const float* __restrict__ W2, const float* __restrict__ W3,
    unsigned short* __restrict__ Wt) {
  __shared__ float Tl[64][68];
  const float* W = (blockIdx.z == 0) ? W0 : (blockIdx.z == 1) ? W1
                   : (blockIdx.z == 2) ? W2 : W3;
  unsigned short* dst = Wt + (size_t)blockIdx.z * 262144;
  const int t = threadIdx.x;
  const int k0 = blockIdx.x * 64, n0 = blockIdx.y * 64;
#pragma unroll
  for (int i = 0; i < 4; ++i) {
    const int idx = t + 256 * i;
    const int row = idx >> 4, cq = (idx & 15) * 4;
    *(float4*)&Tl[row][cq] = *(const float4*)&W[(size_t)(k0 + row) * 512 + n0 + cq];
  }
  __syncthreads();
#pragma unroll
  for (int i = 0; i < 4; ++i) {
    const int idx = t + 256 * i;
    const int nr = idx >> 4, kq = (idx & 15) * 4;
    ushort4 o;
    o.x = f2bf(Tl[kq + 0][nr]);
    o.y = f2bf(Tl[kq + 1][nr]);
    o.z = f2bf(Tl[kq + 2][nr]);
    o.w = f2bf(Tl[kq + 3][nr]);
    *(ushort4*)&dst[(size_t)(n0 + nr) * 512 + k0 + kq] = o;
  }
}

// ---------------------------------------------------------------------------
// Staged QKV projection + stats. 128 rows x 64 cols (one head) per block.
// grid (32 rowtiles, 8 heads, 3 modes). LDS-staged A/B via global_load_lds,
// ds_read_b128 fragments, 2-barrier K-loop (m97 structure).
// mode 0: Q bf16 [bh][n][64] + c1/dv/q2. mode 1: K swizzled tiles + k2/k2max.
// mode 2: V swizzled tiles (rows=dim, cols=key).
// ---------------------------------------------------------------------------
__global__ __launch_bounds__(256) void gemm_qkv(
    const unsigned short* __restrict__ A, const unsigned short* __restrict__ Wt3,
    const float* __restrict__ bq, const float* __restrict__ bk,
    const float* __restrict__ bvv, unsigned short* __restrict__ Qb,
    unsigned short* __restrict__ Ksw, unsigned short* __restrict__ Vsw,
    float* __restrict__ c1a, float* __restrict__ dva, float* __restrict__ k2a,
    float* __restrict__ q2a, unsigned int* __restrict__ k2max) {
  __shared__ __align__(16) unsigned short S[12288];  // As[128][64] | Bs[64][64]
  __shared__ float wmax[4];

  const int which = blockIdx.z;
  const unsigned short* Wt = Wt3 + (size_t)which * 262144;
  const float* bias = (which == 0) ? bq : (which == 1) ? bk : bvv;

  const int t = threadIdx.x;
  const int w = t >> 6, lane = t & 63, ln = lane & 15, quad = lane >> 4;
  const int r0 = blockIdx.x * 128, h = blockIdx.y;
  const int c0 = h * 64;
  const int b = r0 >> 11, n0 = r0 & 2047;
  const int bh = b * HH + h;

  f32x4 acc[2][4];
#pragma unroll
  for (int rf = 0; rf < 2; ++rf)
#pragma unroll
    for (int nt = 0; nt < 4; ++nt) acc[rf][nt] = (f32x4)(0.0f);

  const int lr = lane >> 3, lc = (lane & 7) * 8;  // 8 lanes per 128B row

  for (int k0 = 0; k0 < 512; k0 += 64) {
    // stage A rows w*32..w*32+31 (4 instr), B rows w*16..w*16+15 (2 instr)
#pragma unroll
    for (int i = 0; i < 4; ++i)
      async16(A + (size_t)(r0 + w * 32 + i * 8 + lr) * 512 + k0 + lc,
              S + (w * 32 + i * 8) * 64);
#pragma unroll
    for (int i = 0; i < 2; ++i)
      async16(Wt + (size_t)(c0 + w * 16 + i * 8 + lr) * 512 + k0 + lc,
              S + 8192 + (w * 16 + i * 8) * 64);
    __syncthreads();
#pragma unroll
    for (int kk = 0; kk < 64; kk += 32) {
      bf16x8 af[2];
#pragma unroll
      for (int rf = 0; rf < 2; ++rf)
        af[rf] = *(const bf16x8*)&S[(w * 32 + rf * 16 + ln) * 64 + kk + quad * 8];
#pragma unroll
      for (int nt = 0; nt < 4; ++nt) {
        const bf16x8 bf = *(const bf16x8*)&S[8192 + (nt * 16 + ln) * 64 + kk + quad * 8];
#pragma unroll
        for (int rf = 0; rf < 2; ++rf)
          acc[rf][nt] = __builtin_amdgcn_mfma_f32_16x16x32_bf16(af[rf], bf, acc[rf][nt], 0, 0, 0);
      }
    }
    __syncthreads();
  }

  // bias into regs
  float x[2][4][4];  // [rf][nt][r]
#pragma unroll
  for (int nt = 0; nt < 4; ++nt) {
    const float bv = bias[c0 + nt * 16 + ln];
#pragma unroll
    for (int rf = 0; rf < 2; ++rf)
#pragma unroll
      for (int r = 0; r < 4; ++r) x[rf][nt][r] = acc[rf][nt][r] + bv;
  }

  if (which == 0) {
#pragma unroll
    for (int rf = 0; rf < 2; ++rf)
#pragma unroll
      for (int r = 0; r < 4; ++r) {
        float s1 = x[rf][0][r] + x[rf][1][r] + x[rf][2][r] + x[rf][3][r];
#pragma unroll
        for (int off = 1; off < 16; off <<= 1) s1 += __shfl_xor(s1, off, 64);
        const float mu = s1 * (1.0f / 64.0f);
        float s2 = 0.0f, sa = 0.0f;
#pragma unroll
        for (int nt = 0; nt < 4; ++nt) {
          const float dx = x[rf][nt][r] - mu;
          s2 += dx * dx;
          sa += fabsf(dx);
        }
#pragma unroll
        for (int off = 1; off < 16; off <<= 1) {
          s2 += __shfl_xor(s2, off, 64);
          sa += __shfl_xor(sa, off, 64);
        }
        if (ln == 0) {
          const float sigma = sqrtf(s2 * (1.0f / 64.0f) + EPSF);
          const float nf = sa / (sigma + EPSF);
          const float dInv = 1.0f / (__expf(-nf) + 1.0f);
          const int row = bh * NNq + n0 + w * 32 + rf * 16 + quad * 4 + r;
          c1a[row] = (0.125f + 2.0f * dInv) * LOG2E;
          dva[row] = dInv * LOG2E;
          q2a[row] = s2 + 64.0f * mu * mu;
        }
      }
    // stage bf16 Q [128][72] and store coalesced
#pragma unroll
    for (int rf = 0; rf < 2; ++rf)
#pragma unroll
      for (int nt = 0; nt < 4; ++nt)
#pragma unroll
        for (int r = 0; r < 4; ++r)
          S[(w * 32 + rf * 16 + quad * 4 + r) * 72 + nt * 16 + ln] = f2bf(x[rf][nt][r]);
    __syncthreads();
#pragma unroll
    for (int i = 0; i < 4; ++i) {
      const int idx = t + 256 * i;
      const int q = idx >> 3, c = idx & 7;
      *(uint4*)&Qb[((size_t)bh * NNq + n0 + q) * 64 + c * 8] =
          *(const uint4*)&S[q * 72 + c * 8];
    }
  } else if (which == 1) {
    float mx = 0.0f;
#pragma unroll
    for (int rf = 0; rf < 2; ++rf)
#pragma unroll
      for (int r = 0; r < 4; ++r) {
        float s2 = 0.0f;
#pragma unroll
        for (int nt = 0; nt < 4; ++nt) s2 += x[rf][nt][r] * x[rf][nt][r];
#pragma unroll
        for (int off = 1; off < 16; off <<= 1) s2 += __shfl_xor(s2, off, 64);
        if (ln == 0) k2a[bh * NNq + n0 + w * 32 + rf * 16 + quad * 4 + r] = s2;
        mx = fmaxf(mx, s2);
      }
#pragma unroll
    for (int off = 16; off < 64; off <<= 1) mx = fmaxf(mx, __shfl_xor(mx, off, 64));
    if (lane == 0) wmax[w] = mx;
    // swizzled K tiles: 2 tiles of 64 keys
#pragma unroll
    for (int rf = 0; rf < 2; ++rf)
#pragma unroll
      for (int nt = 0; nt < 4; ++nt) {
        const int c = nt * 2 + (ln >> 3);
#pragma unroll
        for (int r = 0; r < 4; ++r) {
          const int key = w * 32 + rf * 16 + quad * 4 + r;
          const int klo = key & 63;
          S[(key >> 6) * 4096 + klo * 64 + ((c ^ (klo & 7)) * 8) + (ln & 7)] =
              f2bf(x[rf][nt][r]);
        }
      }
    __syncthreads();
    if (t == 0) {
      const float m = fmaxf(fmaxf(wmax[0], wmax[1]), fmaxf(wmax[2], wmax[3]));
      atomicMax(&k2max[bh * 16], __float_as_uint(m));
    }
    unsigned short* dst = Ksw + ((size_t)bh * 32 + (n0 >> 6)) * 4096;
#pragma unroll
    for (int i = 0; i < 4; ++i) {
      const int idx = t + 256 * i;
      *(uint4*)&dst[idx * 8] = *(const uint4*)&S[idx * 8];
    }
  } else {
    // V: buffer [d][128] with per-64 swizzle, then 2 tiles out
#pragma unroll
    for (int rf = 0; rf < 2; ++rf)
#pragma unroll
      for (int nt = 0; nt < 4; ++nt) {
        const int d = nt * 16 + ln;
#pragma unroll
        for (int r = 0; r < 4; ++r) {
          const int key = w * 32 + rf * 16 + quad * 4 + r;
          const int klo = key & 63;
          S[d * 128 + (key >> 6) * 64 + (((klo >> 3) ^ (d & 7)) * 8) + (klo & 7)] =
              f2bf(x[rf][nt][r]);
        }
      }
    __syncthreads();
    unsigned short* dst = Vsw + ((size_t)bh * 32 + (n0 >> 6)) * 4096;
#pragma unroll
    for (int i = 0; i < 4; ++i) {
      const int g = t + 256 * i;  // uint4 index
      const int tile = g >> 9, d = (g >> 3) & 63, j8 = (g & 7) * 8;
      *(uint4*)&dst[tile * 4096 + d * 64 + j8] =
          *(const uint4*)&S[d * 128 + tile * 64 + j8];
    }
  }
}

// ---------------------------------------------------------------------------
// Flash attention: block = 64 queries x bh, 4 waves. S^T orientation:
// MFMA(Kfrag, Qfrag) -> each lane owns ONE query (col) and 4-consec keys
// (rows) => scalar softmax state, ds_write_b64 for the P transpose.
// ---------------------------------------------------------------------------
__global__ __launch_bounds__(256) void attn_kernel(
    const unsigned short* __restrict__ Qb, const unsigned short* __restrict__ Ksw,
    const unsigned short* __restrict__ Vsw, const float* __restrict__ c1a,
    const float* __restrict__ dva, const float* __restrict__ k2a,
    const float* __restrict__ q2a, const unsigned int* __restrict__ k2maxu,
    unsigned short* __restrict__ attnb) {
  __shared__ __align__(16) unsigned short Kt[4096];
  __shared__ __align__(16) unsigned short Vt[4096];
  __shared__ __align__(16) unsigned short Ps[64 * 72];
  __shared__ __align__(16) float k2t[64];

  const int t = threadIdx.x;
  const int w = t >> 6, lane = t & 63, ln = lane & 15, quad = lane >> 4;
  const int qt = blockIdx.x, bh = blockIdx.y;
  const int b = bh >> 3, h = bh & 7;
  const int q0 = qt * 64;
  const int rowbase = bh * NNq;

  // Q fragment: lane ln holds query q0 + w*16 + ln (B-operand for S^T).
  const int qg = q0 + w * 16 + ln;
  const unsigned short* qrow = Qb + ((size_t)rowbase + qg) * 64;
  const bf16x8 aq0 = *(const bf16x8*)(qrow + quad * 8);
  const bf16x8 aq1 = *(const bf16x8*)(qrow + 32 + quad * 8);

  const float k2m = __uint_as_float(k2maxu[bh * 16]);
  const float c1q = c1a[rowbase + qg];
  const float dvq = dva[rowbase + qg];
  const float Mqq = c1q * sqrtf(q2a[rowbase + qg] * k2m);
  float L = 0.0f;
  f32x4 O[4];
#pragma unroll
  for (int nt = 0; nt < 4; ++nt) O[nt] = (f32x4)(0.0f);

  const unsigned short* Kg = Ksw + (size_t)bh * 32 * 4096;
  const unsigned short* Vg = Vsw + (size_t)bh * 32 * 4096;
  const float* k2g = k2a + rowbase;
  const int sw = quad ^ (ln & 7);
  const int sw1 = (4 + quad) ^ (ln & 7);

  for (int kt = 0; kt < 32; ++kt) {
    {
      const size_t tb = (size_t)kt * 4096 + w * 1024;
      async16(Kg + tb + lane * 8, Kt + w * 1024);
      async16(Kg + tb + 512 + lane * 8, Kt + w * 1024 + 512);
      async16(Vg + tb + lane * 8, Vt + w * 1024);
      async16(Vg + tb + 512 + lane * 8, Vt + w * 1024 + 512);
      if (w == 0) async4(k2g + kt * 64 + lane, k2t);
    }
    __syncthreads();

    // ---- S^T = K Q^T : rows = keys (quad*4+r within nt), col = this lane's q
    f32x4 s[4];
#pragma unroll
    for (int nt = 0; nt < 4; ++nt) {
      const unsigned short* kb = Kt + (nt * 16 + ln) * 64;
      const bf16x8 b0 = *(const bf16x8*)(kb + sw * 8);
      const bf16x8 b1 = *(const bf16x8*)(kb + sw1 * 8);
      f32x4 a = (f32x4)(0.0f);
      a = __builtin_amdgcn_mfma_f32_16x16x32_bf16(b0, aq0, a, 0, 0, 0);
      a = __builtin_amdgcn_mfma_f32_16x16x32_bf16(b1, aq1, a, 0, 0, 0);
      s[nt] = a;
    }

    // ---- softmax (scalar per lane) + packed P^T write (4 bf16 = b64) ----
#pragma unroll
    for (int nt = 0; nt < 4; ++nt) {
      const f32x4 k2v = *(const f32x4*)&k2t[nt * 16 + quad * 4];
      ushort4 pk;
      float p0 = __builtin_amdgcn_exp2f(c1q * s[nt][0] - dvq * k2v[0] - Mqq);
      float p1 = __builtin_amdgcn_exp2f(c1q * s[nt][1] - dvq * k2v[1] - Mqq);
      float p2 = __builtin_amdgcn_exp2f(c1q * s[nt][2] - dvq * k2v[2] - Mqq);
      float p3 = __builtin_amdgcn_exp2f(c1q * s[nt][3] - dvq * k2v[3] - Mqq);
      L += (p0 + p1) + (p2 + p3);
      pk.x = f2bf(p0); pk.y = f2bf(p1); pk.z = f2bf(p2); pk.w = f2bf(p3);
      *(ushort4*)&Ps[(w * 16 + ln) * 72 + nt * 16 + quad * 4] = pk;
    }
    const unsigned short* pr = Ps + (w * 16 + ln) * 72;
    const bf16x8 pa0 = *(const bf16x8*)(pr + quad * 8);
    const bf16x8 pa1 = *(const bf16x8*)(pr + 32 + quad * 8);

    // ---- O += P V ----
#pragma unroll
    for (int nt = 0; nt < 4; ++nt) {
      const unsigned short* vb = Vt + (nt * 16 + ln) * 64;
      const bf16x8 vb0 = *(const bf16x8*)(vb + sw * 8);
      const bf16x8 vb1 = *(const bf16x8*)(vb + sw1 * 8);
      O[nt] = __builtin_amdgcn_mfma_f32_16x16x32_bf16(pa0, vb0, O[nt], 0, 0, 0);
      O[nt] = __builtin_amdgcn_mfma_f32_16x16x32_bf16(pa1, vb1, O[nt], 0, 0, 0);
    }
    __syncthreads();
  }

  // ---- finalize: L lives at lane ln == q-local; reduce across quads ----
  L += __shfl_xor(L, 16, 64);
  L += __shfl_xor(L, 32, 64);
  float inv[4];
#pragma unroll
  for (int r = 0; r < 4; ++r) {
    const float Lr = __shfl(L, quad * 4 + r, 64);  // any lane with ln==q'
    inv[r] = 1.0f / Lr;
  }
#pragma unroll
  for (int nt = 0; nt < 4; ++nt)
#pragma unroll
    for (int r = 0; r < 4; ++r)
      Ps[(w * 16 + quad * 4 + r) * 72 + nt * 16 + ln] = f2bf(O[nt][r] * inv[r]);
  __syncthreads();
#pragma unroll
  for (int i = 0; i < 2; ++i) {
    const int idx = t + 256 * i;
    const int q = idx >> 3, c = idx & 7;
    *(uint4*)&attnb[((size_t)(b * NNq + q0 + q)) * 512 + h * 64 + c * 8] =
        *(const uint4*)&Ps[q * 72 + c * 8];
  }
}

// ---------------------------------------------------------------------------
// Staged out projection: out fp32 = attnb bf16 [4096,512] @ WoT + bo.
// 64x64 tiles, LDS-staged A/B, grid (64,8) = 512 blocks.
// ---------------------------------------------------------------------------
__global__ __launch_bounds__(256) void gemm_out(
    const unsigned short* __restrict__ A, const unsigned short* __restrict__ Wt,
    const float* __restrict__ bias, float* __restrict__ of) {
  __shared__ __align__(16) unsigned short S[8192];  // As[64][64] | Bs[64][64]
  __shared__ float Tl[64][68];
  const int t = threadIdx.x;
  const int w = t >> 6, lane = t & 63, ln = lane & 15, quad = lane >> 4;
  const int r0 = blockIdx.x * 64, c0 = blockIdx.y * 64;
  const int lr = lane >> 3, lc = (lane & 7) * 8;

  f32x4 acc[4];
#pragma unroll
  for (int nt = 0; nt < 4; ++nt) acc[nt] = (f32x4)(0.0f);

  for (int k0 = 0; k0 < 512; k0 += 64) {
#pragma unroll
    for (int i = 0; i < 2; ++i) {
      async16(A + (size_t)(r0 + w * 16 + i * 8 + lr) * 512 + k0 + lc,
              S + (w * 16 + i * 8) * 64);
      async16(Wt + (size_t)(c0 + w * 16 + i * 8 + lr) * 512 + k0 + lc,
              S + 4096 + (w * 16 + i * 8) * 64);
    }
    __syncthreads();
#pragma unroll
    for (int kk = 0; kk < 64; kk += 32) {
      const bf16x8 af = *(const bf16x8*)&S[(w * 16 + ln) * 64 + kk + quad * 8];
#pragma unroll
      for (int nt = 0; nt < 4; ++nt) {
        const bf16x8 bf = *(const bf16x8*)&S[4096 + (nt * 16 + ln) * 64 + kk + quad * 8];
        acc[nt] = __builtin_amdgcn_mfma_f32_16x16x32_bf16(af, bf, acc[nt], 0, 0, 0);
      }
    }
    __syncthreads();
  }
#pragma unroll
  for (int nt = 0; nt < 4; ++nt) {
    const float bv = bias[c0 + nt * 16 + ln];
#pragma unroll
    for (int r = 0; r < 4; ++r)
      Tl[w * 16 + quad * 4 + r][nt * 16 + ln] = acc[nt][r] + bv;
  }
  __syncthreads();
#pragma unroll
  for (int i = 0; i < 4; ++i) {
    const int idx = t + 256 * i;
    const int row = idx >> 4, c4 = (idx & 15) * 4;
    *(float4*)&of[(size_t)(r0 + row) * 512 + c0 + c4] = *(const float4*)&Tl[row][c4];
  }
}

// ---------------------------------------------------------------------------
extern "C" void kernel_launch(void* const* d_in, const int* in_sizes, int n_in,
                              void* d_out, int out_size, void* d_ws,
                              size_t ws_size, hipStream_t stream) {
  const float* z = (const float*)d_in[0];
  const float* Wq = (const float*)d_in[1];
  const float* bq = (const float*)d_in[2];
  const float* Wk = (const float*)d_in[3];
  const float* bk = (const float*)d_in[4];
  const float* Wv = (const float*)d_in[5];
  const float* bv = (const float*)d_in[6];
  const float* Wo = (const float*)d_in[7];
  const float* bo = (const float*)d_in[8];
  float* out = (float*)d_out;

  char* ws = (char*)d_ws;
  unsigned short* zb = (unsigned short*)(ws);                // 4 MiB
  unsigned short* Wt = (unsigned short*)(ws + 4194304);      // 2 MiB
  unsigned short* Qb = (unsigned short*)(ws + 6291456);      // 4 MiB
  unsigned short* Ksw = (unsigned short*)(ws + 10485760);    // 4 MiB
  unsigned short* Vsw = (unsigned short*)(ws + 14680064);    // 4 MiB
  float* c1 = (float*)(ws + 18874368);                       // 128 KiB each
  float* dv = (float*)(ws + 19005440);
  float* k2 = (float*)(ws + 19136512);
  float* q2 = (float*)(ws + 19267584);
  unsigned short* attnb = (unsigned short*)(ws + 19398656);  // 4 MiB
  unsigned int* k2max = (unsigned int*)(ws + 23592960);      // 1 KiB

  hipLaunchKernelGGL(convert_z, dim3(1024), dim3(256), 0, stream, z, zb);
  hipLaunchKernelGGL(transw_kernel, dim3(8, 8, 4), dim3(256), 0, stream,
                     Wq, Wk, Wv, Wo, Wt);
  hipMemsetAsync(k2max, 0, 1024, stream);
  hipLaunchKernelGGL(gemm_qkv, dim3(32, 8, 3), dim3(256), 0, stream, zb, Wt,
                     bq, bk, bv, Qb, Ksw, Vsw, c1, dv, k2, q2, k2max);
  hipLaunchKernelGGL(attn_kernel, dim3(32, 16), dim3(256), 0, stream, Qb, Ksw,
                     Vsw, c1, dv, k2, q2, k2max, attnb);
  hipLaunchKernelGGL(gemm_out, dim3(64, 8), dim3(256), 0, stream, attnb,
                     Wt + 786432, bo, out);
}

// Round 6
// 142.429 us; speedup vs baseline: 2.7356x; 1.0440x over previous
//
#include <hip/hip_runtime.h>
#include <hip/hip_bf16.h>

#define HH 8
#define NNq 2048
#define EPSF 1e-5f
#define LOG2E 1.4426950408889634f

typedef __bf16 bf16x8 __attribute__((ext_vector_type(8)));
typedef float f32x4 __attribute__((ext_vector_type(4)));

typedef const __attribute__((address_space(1))) unsigned int* gas_t;
typedef __attribute__((address_space(3))) unsigned int* las_t;

__device__ __forceinline__ void async16(const void* g, void* l) {
  __builtin_amdgcn_global_load_lds((gas_t)g, (las_t)l, 16, 0, 0);
}
__device__ __forceinline__ void async4(const void* g, void* l) {
  __builtin_amdgcn_global_load_lds((gas_t)g, (las_t)l, 4, 0, 0);
}

__device__ __forceinline__ unsigned short f2bf(float f) {
  union { float f; unsigned int u; } a;
  a.f = f;
  unsigned int r = a.u + 0x7fffu + ((a.u >> 16) & 1u);
  return (unsigned short)(r >> 16);
}

// ---------------------------------------------------------------------------
// prep: blocks [0,1024) convert z fp32->bf16; [1024,1280) transpose weights
// fp32->bf16 [n][k]; block 1280 zeroes k2max.
// ---------------------------------------------------------------------------
__global__ __launch_bounds__(256) void prep_kernel(
    const float* __restrict__ z, const float* __restrict__ W0,
    const float* __restrict__ W1, const float* __restrict__ W2,
    const float* __restrict__ W3, unsigned short* __restrict__ zb,
    unsigned short* __restrict__ Wt, unsigned int* __restrict__ k2max) {
  __shared__ float Tl[64][68];
  const int t = threadIdx.x;
  const int bx = blockIdx.x;
  if (bx < 1024) {
    const int i = (bx * 256 + t) * 8;
    const float4 a = *(const float4*)&z[i];
    const float4 b = *(const float4*)&z[i + 4];
    union { unsigned short us[8]; uint4 v; } o;
    o.us[0] = f2bf(a.x); o.us[1] = f2bf(a.y); o.us[2] = f2bf(a.z); o.us[3] = f2bf(a.w);
    o.us[4] = f2bf(b.x); o.us[5] = f2bf(b.y); o.us[6] = f2bf(b.z); o.us[7] = f2bf(b.w);
    *(uint4*)&zb[i] = o.v;
  } else if (bx < 1280) {
    const int idx0 = bx - 1024;
    const int wsel = idx0 >> 6, rem = idx0 & 63;
    const int k0 = (rem >> 3) * 64, n0 = (rem & 7) * 64;
    const float* W = (wsel == 0) ? W0 : (wsel == 1) ? W1 : (wsel == 2) ? W2 : W3;
    unsigned short* dst = Wt + (size_t)wsel * 262144;
#pragma unroll
    for (int i = 0; i < 4; ++i) {
      const int idx = t + 256 * i;
      const int row = idx >> 4, cq = (idx & 15) * 4;
      *(float4*)&Tl[row][cq] = *(const float4*)&W[(size_t)(k0 + row) * 512 + n0 + cq];
    }
    __syncthreads();
#pragma unroll
    for (int i = 0; i < 4; ++i) {
      const int idx = t + 256 * i;
      const int nr = idx >> 4, kq = (idx & 15) * 4;
      ushort4 o;
      o.x = f2bf(Tl[kq + 0][nr]);
      o.y = f2bf(Tl[kq + 1][nr]);
      o.z = f2bf(Tl[kq + 2][nr]);
      o.w = f2bf(Tl[kq + 3][nr]);
      *(ushort4*)&dst[(size_t)(n0 + nr) * 512 + k0 + kq] = o;
    }
  } else {
    k2max[t] = 0u;
  }
}

// ---------------------------------------------------------------------------
// Staged QKV projection + stats. 128 rows x 64 cols (one head) per block.
// grid (32 rowtiles, 8 heads, 3 modes). m97-style 2-barrier K-loop.
// mode 0: Q bf16 [bh][n][64] + c1/dv/q2. mode 1: K swizzled tiles + k2/k2max.
// mode 2: V swizzled tiles (rows=dim, cols=key).
// ---------------------------------------------------------------------------
__global__ __launch_bounds__(256) void gemm_qkv(
    const unsigned short* __restrict__ A, const unsigned short* __restrict__ Wt3,
    const float* __restrict__ bq, const float* __restrict__ bk,
    const float* __restrict__ bvv, unsigned short* __restrict__ Qb,
    unsigned short* __restrict__ Ksw, unsigned short* __restrict__ Vsw,
    float* __restrict__ c1a, float* __restrict__ dva, float* __restrict__ k2a,
    float* __restrict__ q2a, unsigned int* __restrict__ k2max) {
  __shared__ __align__(16) unsigned short S[12288];  // As[128][64] | Bs[64][64]
  __shared__ float wmax[4];

  const int which = blockIdx.z;
  const unsigned short* Wt = Wt3 + (size_t)which * 262144;
  const float* bias = (which == 0) ? bq : (which == 1) ? bk : bvv;

  const int t = threadIdx.x;
  const int w = t >> 6, lane = t & 63, ln = lane & 15, quad = lane >> 4;
  const int r0 = blockIdx.x * 128, h = blockIdx.y;
  const int c0 = h * 64;
  const int b = r0 >> 11, n0 = r0 & 2047;
  const int bh = b * HH + h;

  f32x4 acc[2][4];
#pragma unroll
  for (int rf = 0; rf < 2; ++rf)
#pragma unroll
    for (int nt = 0; nt < 4; ++nt) acc[rf][nt] = (f32x4)(0.0f);

  const int lr = lane >> 3, lc = (lane & 7) * 8;

  for (int k0 = 0; k0 < 512; k0 += 64) {
#pragma unroll
    for (int i = 0; i < 4; ++i)
      async16(A + (size_t)(r0 + w * 32 + i * 8 + lr) * 512 + k0 + lc,
              S + (w * 32 + i * 8) * 64);
#pragma unroll
    for (int i = 0; i < 2; ++i)
      async16(Wt + (size_t)(c0 + w * 16 + i * 8 + lr) * 512 + k0 + lc,
              S + 8192 + (w * 16 + i * 8) * 64);
    __syncthreads();
#pragma unroll
    for (int kk = 0; kk < 64; kk += 32) {
      bf16x8 af[2];
#pragma unroll
      for (int rf = 0; rf < 2; ++rf)
        af[rf] = *(const bf16x8*)&S[(w * 32 + rf * 16 + ln) * 64 + kk + quad * 8];
#pragma unroll
      for (int nt = 0; nt < 4; ++nt) {
        const bf16x8 bf = *(const bf16x8*)&S[8192 + (nt * 16 + ln) * 64 + kk + quad * 8];
#pragma unroll
        for (int rf = 0; rf < 2; ++rf)
          acc[rf][nt] = __builtin_amdgcn_mfma_f32_16x16x32_bf16(af[rf], bf, acc[rf][nt], 0, 0, 0);
      }
    }
    __syncthreads();
  }

  float x[2][4][4];  // [rf][nt][r]
#pragma unroll
  for (int nt = 0; nt < 4; ++nt) {
    const float bv = bias[c0 + nt * 16 + ln];
#pragma unroll
    for (int rf = 0; rf < 2; ++rf)
#pragma unroll
      for (int r = 0; r < 4; ++r) x[rf][nt][r] = acc[rf][nt][r] + bv;
  }

  if (which == 0) {
#pragma unroll
    for (int rf = 0; rf < 2; ++rf)
#pragma unroll
      for (int r = 0; r < 4; ++r) {
        float s1 = x[rf][0][r] + x[rf][1][r] + x[rf][2][r] + x[rf][3][r];
#pragma unroll
        for (int off = 1; off < 16; off <<= 1) s1 += __shfl_xor(s1, off, 64);
        const float mu = s1 * (1.0f / 64.0f);
        float s2 = 0.0f, sa = 0.0f;
#pragma unroll
        for (int nt = 0; nt < 4; ++nt) {
          const float dx = x[rf][nt][r] - mu;
          s2 += dx * dx;
          sa += fabsf(dx);
        }
#pragma unroll
        for (int off = 1; off < 16; off <<= 1) {
          s2 += __shfl_xor(s2, off, 64);
          sa += __shfl_xor(sa, off, 64);
        }
        if (ln == 0) {
          const float sigma = sqrtf(s2 * (1.0f / 64.0f) + EPSF);
          const float nf = sa / (sigma + EPSF);
          const float dInv = 1.0f / (__expf(-nf) + 1.0f);
          const int row = bh * NNq + n0 + w * 32 + rf * 16 + quad * 4 + r;
          c1a[row] = (0.125f + 2.0f * dInv) * LOG2E;
          dva[row] = dInv * LOG2E;
          q2a[row] = s2 + 64.0f * mu * mu;
        }
      }
#pragma unroll
    for (int rf = 0; rf < 2; ++rf)
#pragma unroll
      for (int nt = 0; nt < 4; ++nt)
#pragma unroll
        for (int r = 0; r < 4; ++r)
          S[(w * 32 + rf * 16 + quad * 4 + r) * 72 + nt * 16 + ln] = f2bf(x[rf][nt][r]);
    __syncthreads();
#pragma unroll
    for (int i = 0; i < 4; ++i) {
      const int idx = t + 256 * i;
      const int q = idx >> 3, c = idx & 7;
      *(uint4*)&Qb[((size_t)bh * NNq + n0 + q) * 64 + c * 8] =
          *(const uint4*)&S[q * 72 + c * 8];
    }
  } else if (which == 1) {
    float mx = 0.0f;
#pragma unroll
    for (int rf = 0; rf < 2; ++rf)
#pragma unroll
      for (int r = 0; r < 4; ++r) {
        float s2 = 0.0f;
#pragma unroll
        for (int nt = 0; nt < 4; ++nt) s2 += x[rf][nt][r] * x[rf][nt][r];
#pragma unroll
        for (int off = 1; off < 16; off <<= 1) s2 += __shfl_xor(s2, off, 64);
        if (ln == 0) k2a[bh * NNq + n0 + w * 32 + rf * 16 + quad * 4 + r] = s2;
        mx = fmaxf(mx, s2);
      }
#pragma unroll
    for (int off = 16; off < 64; off <<= 1) mx = fmaxf(mx, __shfl_xor(mx, off, 64));
    if (lane == 0) wmax[w] = mx;
#pragma unroll
    for (int rf = 0; rf < 2; ++rf)
#pragma unroll
      for (int nt = 0; nt < 4; ++nt) {
        const int c = nt * 2 + (ln >> 3);
#pragma unroll
        for (int r = 0; r < 4; ++r) {
          const int key = w * 32 + rf * 16 + quad * 4 + r;
          const int klo = key & 63;
          S[(key >> 6) * 4096 + klo * 64 + ((c ^ (klo & 7)) * 8) + (ln & 7)] =
              f2bf(x[rf][nt][r]);
        }
      }
    __syncthreads();
    if (t == 0) {
      const float m = fmaxf(fmaxf(wmax[0], wmax[1]), fmaxf(wmax[2], wmax[3]));
      atomicMax(&k2max[bh * 16], __float_as_uint(m));
    }
    unsigned short* dst = Ksw + ((size_t)bh * 32 + (n0 >> 6)) * 4096;
#pragma unroll
    for (int i = 0; i < 4; ++i) {
      const int idx = t + 256 * i;
      *(uint4*)&dst[idx * 8] = *(const uint4*)&S[idx * 8];
    }
  } else {
#pragma unroll
    for (int rf = 0; rf < 2; ++rf)
#pragma unroll
      for (int nt = 0; nt < 4; ++nt) {
        const int d = nt * 16 + ln;
#pragma unroll
        for (int r = 0; r < 4; ++r) {
          const int key = w * 32 + rf * 16 + quad * 4 + r;
          const int klo = key & 63;
          S[d * 128 + (key >> 6) * 64 + (((klo >> 3) ^ (d & 7)) * 8) + (klo & 7)] =
              f2bf(x[rf][nt][r]);
        }
      }
    __syncthreads();
    unsigned short* dst = Vsw + ((size_t)bh * 32 + (n0 >> 6)) * 4096;
#pragma unroll
    for (int i = 0; i < 4; ++i) {
      const int g = t + 256 * i;
      const int tile = g >> 9, d = (g >> 3) & 63, j8 = (g & 7) * 8;
      *(uint4*)&dst[tile * 4096 + d * 64 + j8] =
          *(const uint4*)&S[d * 128 + tile * 64 + j8];
    }
  }
}

// ---------------------------------------------------------------------------
// Flash attention, 512 threads = 8 waves: waves 0-3 keys [0,1024),
// waves 4-7 keys [1024,2048). Per-half K/V/Ps/k2 LDS buffers; fixed-bound
// softmax => partials combine by pure addition (shared shift Mq).
// S^T orientation (lane owns one query); end: in-LDS O/L sum + normalize.
// ---------------------------------------------------------------------------
__global__ __launch_bounds__(512) void attn_kernel(
    const unsigned short* __restrict__ Qb, const unsigned short* __restrict__ Ksw,
    const unsigned short* __restrict__ Vsw, const float* __restrict__ c1a,
    const float* __restrict__ dva, const float* __restrict__ k2a,
    const float* __restrict__ q2a, const unsigned int* __restrict__ k2maxu,
    unsigned short* __restrict__ attnb) {
  // [0,32768): per-half K(8K)+V(8K); aliased as fp32 O partials at the end.
  // [32768,51200): per-half Ps [64][72] bf16; aliased as L storage.
  // [51200,51712): per-half k2 tile.
  __shared__ __align__(16) char smem[51712];

  const int t = threadIdx.x;
  const int w8 = t >> 6, lane = t & 63, ln = lane & 15, quad = lane >> 4;
  const int half = w8 >> 2, wl = w8 & 3;
  const int qt = blockIdx.x, bh = blockIdx.y;
  const int b = bh >> 3, h = bh & 7;
  const int q0 = qt * 64;
  const int rowbase = bh * NNq;

  unsigned short* Kt = (unsigned short*)(smem + half * 16384);
  unsigned short* Vt = (unsigned short*)(smem + half * 16384 + 8192);
  unsigned short* Ps = (unsigned short*)(smem + 32768 + half * 9216);
  float* k2t = (float*)(smem + 51200 + half * 256);

  // Q fragment: lane ln holds query q0 + wl*16 + ln (B-operand for S^T).
  const int qg = q0 + wl * 16 + ln;
  const unsigned short* qrow = Qb + ((size_t)rowbase + qg) * 64;
  const bf16x8 aq0 = *(const bf16x8*)(qrow + quad * 8);
  const bf16x8 aq1 = *(const bf16x8*)(qrow + 32 + quad * 8);

  const float k2m = __uint_as_float(k2maxu[bh * 16]);
  const float c1q = c1a[rowbase + qg];
  const float dvq = dva[rowbase + qg];
  const float Mqq = c1q * sqrtf(q2a[rowbase + qg] * k2m);
  float L = 0.0f;
  f32x4 O[4];
#pragma unroll
  for (int nt = 0; nt < 4; ++nt) O[nt] = (f32x4)(0.0f);

  const unsigned short* Kg = Ksw + (size_t)bh * 32 * 4096;
  const unsigned short* Vg = Vsw + (size_t)bh * 32 * 4096;
  const float* k2g = k2a + rowbase + half * 1024;
  const int sw = quad ^ (ln & 7);
  const int sw1 = (4 + quad) ^ (ln & 7);

  for (int kt = 0; kt < 16; ++kt) {
    {
      const size_t tb = (size_t)(half * 16 + kt) * 4096 + wl * 1024;
      async16(Kg + tb + lane * 8, Kt + wl * 1024);
      async16(Kg + tb + 512 + lane * 8, Kt + wl * 1024 + 512);
      async16(Vg + tb + lane * 8, Vt + wl * 1024);
      async16(Vg + tb + 512 + lane * 8, Vt + wl * 1024 + 512);
      if (wl == 0) async4(k2g + kt * 64 + lane, k2t);
    }
    __syncthreads();

    // ---- S^T = K Q^T ----
    f32x4 s[4];
#pragma unroll
    for (int nt = 0; nt < 4; ++nt) {
      const unsigned short* kb = Kt + (nt * 16 + ln) * 64;
      const bf16x8 b0 = *(const bf16x8*)(kb + sw * 8);
      const bf16x8 b1 = *(const bf16x8*)(kb + sw1 * 8);
      f32x4 a = (f32x4)(0.0f);
      a = __builtin_amdgcn_mfma_f32_16x16x32_bf16(b0, aq0, a, 0, 0, 0);
      a = __builtin_amdgcn_mfma_f32_16x16x32_bf16(b1, aq1, a, 0, 0, 0);
      s[nt] = a;
    }

    // ---- softmax (scalar per lane) + packed P^T write ----
#pragma unroll
    for (int nt = 0; nt < 4; ++nt) {
      const f32x4 k2v = *(const f32x4*)&k2t[nt * 16 + quad * 4];
      ushort4 pk;
      float p0 = __builtin_amdgcn_exp2f(c1q * s[nt][0] - dvq * k2v[0] - Mqq);
      float p1 = __builtin_amdgcn_exp2f(c1q * s[nt][1] - dvq * k2v[1] - Mqq);
      float p2 = __builtin_amdgcn_exp2f(c1q * s[nt][2] - dvq * k2v[2] - Mqq);
      float p3 = __builtin_amdgcn_exp2f(c1q * s[nt][3] - dvq * k2v[3] - Mqq);
      L += (p0 + p1) + (p2 + p3);
      pk.x = f2bf(p0); pk.y = f2bf(p1); pk.z = f2bf(p2); pk.w = f2bf(p3);
      *(ushort4*)&Ps[(wl * 16 + ln) * 72 + nt * 16 + quad * 4] = pk;
    }
    const unsigned short* pr = Ps + (wl * 16 + ln) * 72;
    const bf16x8 pa0 = *(const bf16x8*)(pr + quad * 8);
    const bf16x8 pa1 = *(const bf16x8*)(pr + 32 + quad * 8);

    // ---- O += P V ----
#pragma unroll
    for (int nt = 0; nt < 4; ++nt) {
      const unsigned short* vb = Vt + (nt * 16 + ln) * 64;
      const bf16x8 vb0 = *(const bf16x8*)(vb + sw * 8);
      const bf16x8 vb1 = *(const bf16x8*)(vb + sw1 * 8);
      O[nt] = __builtin_amdgcn_mfma_f32_16x16x32_bf16(pa0, vb0, O[nt], 0, 0, 0);
      O[nt] = __builtin_amdgcn_mfma_f32_16x16x32_bf16(pa1, vb1, O[nt], 0, 0, 0);
    }
    __syncthreads();
  }

  // ---- L: sum across quads (lane holds query wl*16+ln) ----
  L += __shfl_xor(L, 16, 64);
  L += __shfl_xor(L, 32, 64);

  // ---- stage partial O (fp32, aliases K/V) and L (aliases Ps) ----
  float* Ost = (float*)(smem + half * 16384);
  float* Lst = (float*)(smem + 32768 + half * 9216);
#pragma unroll
  for (int nt = 0; nt < 4; ++nt)
#pragma unroll
    for (int r = 0; r < 4; ++r)
      Ost[(wl * 16 + quad * 4 + r) * 64 + nt * 16 + ln] = O[nt][r];
  if (quad == 0) Lst[wl * 16 + ln] = L;
  __syncthreads();

  // ---- combine halves, normalize, write bf16 [B,N,DIM] ----
  const float* O0 = (const float*)smem;
  const float* O1 = (const float*)(smem + 16384);
  const float* L0 = (const float*)(smem + 32768);
  const float* L1 = (const float*)(smem + 32768 + 9216);
  const int q = t >> 3, c8 = (t & 7) * 8;
  const float inv = 1.0f / (L0[q] + L1[q]);
  const int base = q * 64 + c8;
  float4 a0 = *(const float4*)&O0[base];
  float4 a1 = *(const float4*)&O0[base + 4];
  const float4 b0 = *(const float4*)&O1[base];
  const float4 b1 = *(const float4*)&O1[base + 4];
  union { unsigned short us[8]; uint4 v; } ov;
  ov.us[0] = f2bf((a0.x + b0.x) * inv);
  ov.us[1] = f2bf((a0.y + b0.y) * inv);
  ov.us[2] = f2bf((a0.z + b0.z) * inv);
  ov.us[3] = f2bf((a0.w + b0.w) * inv);
  ov.us[4] = f2bf((a1.x + b1.x) * inv);
  ov.us[5] = f2bf((a1.y + b1.y) * inv);
  ov.us[6] = f2bf((a1.z + b1.z) * inv);
  ov.us[7] = f2bf((a1.w + b1.w) * inv);
  *(uint4*)&attnb[((size_t)(b * NNq + q0 + q)) * 512 + h * 64 + c8] = ov.v;
}

// ---------------------------------------------------------------------------
// Staged out projection: out fp32 = attnb bf16 [4096,512] @ WoT + bo.
// 64x64 tiles, grid (64,8) = 512 blocks.
// ---------------------------------------------------------------------------
__global__ __launch_bounds__(256) void gemm_out(
    const unsigned short* __restrict__ A, const unsigned short* __restrict__ Wt,
    const float* __restrict__ bias, float* __restrict__ of) {
  __shared__ __align__(16) unsigned short S[8192];
  __shared__ float Tl[64][68];
  const int t = threadIdx.x;
  const int w = t >> 6, lane = t & 63, ln = lane & 15, quad = lane >> 4;
  const int r0 = blockIdx.x * 64, c0 = blockIdx.y * 64;
  const int lr = lane >> 3, lc = (lane & 7) * 8;

  f32x4 acc[4];
#pragma unroll
  for (int nt = 0; nt < 4; ++nt) acc[nt] = (f32x4)(0.0f);

  for (int k0 = 0; k0 < 512; k0 += 64) {
#pragma unroll
    for (int i = 0; i < 2; ++i) {
      async16(A + (size_t)(r0 + w * 16 + i * 8 + lr) * 512 + k0 + lc,
              S + (w * 16 + i * 8) * 64);
      async16(Wt + (size_t)(c0 + w * 16 + i * 8 + lr) * 512 + k0 + lc,
              S + 4096 + (w * 16 + i * 8) * 64);
    }
    __syncthreads();
#pragma unroll
    for (int kk = 0; kk < 64; kk += 32) {
      const bf16x8 af = *(const bf16x8*)&S[(w * 16 + ln) * 64 + kk + quad * 8];
#pragma unroll
      for (int nt = 0; nt < 4; ++nt) {
        const bf16x8 bf = *(const bf16x8*)&S[4096 + (nt * 16 + ln) * 64 + kk + quad * 8];
        acc[nt] = __builtin_amdgcn_mfma_f32_16x16x32_bf16(af, bf, acc[nt], 0, 0, 0);
      }
    }
    __syncthreads();
  }
#pragma unroll
  for (int nt = 0; nt < 4; ++nt) {
    const float bv = bias[c0 + nt * 16 + ln];
#pragma unroll
    for (int r = 0; r < 4; ++r)
      Tl[w * 16 + quad * 4 + r][nt * 16 + ln] = acc[nt][r] + bv;
  }
  __syncthreads();
#pragma unroll
  for (int i = 0; i < 4; ++i) {
    const int idx = t + 256 * i;
    const int row = idx >> 4, c4 = (idx & 15) * 4;
    *(float4*)&of[(size_t)(r0 + row) * 512 + c0 + c4] = *(const float4*)&Tl[row][c4];
  }
}

// ---------------------------------------------------------------------------
extern "C" void kernel_launch(void* const* d_in, const int* in_sizes, int n_in,
                              void* d_out, int out_size, void* d_ws,
                              size_t ws_size, hipStream_t stream) {
  const float* z = (const float*)d_in[0];
  const float* Wq = (const float*)d_in[1];
  const float* bq = (const float*)d_in[2];
  const float* Wk = (const float*)d_in[3];
  const float* bk = (const float*)d_in[4];
  const float* Wv = (const float*)d_in[5];
  const float* bv = (const float*)d_in[6];
  const float* Wo = (const float*)d_in[7];
  const float* bo = (const float*)d_in[8];
  float* out = (float*)d_out;

  char* ws = (char*)d_ws;
  unsigned short* zb = (unsigned short*)(ws);                // 4 MiB
  unsigned short* Wt = (unsigned short*)(ws + 4194304);      // 2 MiB
  unsigned short* Qb = (unsigned short*)(ws + 6291456);      // 4 MiB
  unsigned short* Ksw = (unsigned short*)(ws + 10485760);    // 4 MiB
  unsigned short* Vsw = (unsigned short*)(ws + 14680064);    // 4 MiB
  float* c1 = (float*)(ws + 18874368);                       // 128 KiB each
  float* dv = (float*)(ws + 19005440);
  float* k2 = (float*)(ws + 19136512);
  float* q2 = (float*)(ws + 19267584);
  unsigned short* attnb = (unsigned short*)(ws + 19398656);  // 4 MiB
  unsigned int* k2max = (unsigned int*)(ws + 23592960);      // 1 KiB

  hipLaunchKernelGGL(prep_kernel, dim3(1281), dim3(256), 0, stream, z, Wq, Wk,
                     Wv, Wo, zb, Wt, k2max);
  hipLaunchKernelGGL(gemm_qkv, dim3(32, 8, 3), dim3(256), 0, stream, zb, Wt,
                     bq, bk, bv, Qb, Ksw, Vsw, c1, dv, k2, q2, k2max);
  hipLaunchKernelGGL(attn_kernel, dim3(32, 16), dim3(512), 0, stream, Qb, Ksw,
                     Vsw, c1, dv, k2, q2, k2max, attnb);
  hipLaunchKernelGGL(gemm_out, dim3(64, 8), dim3(256), 0, stream, attnb,
                     Wt + 786432, bo, out);
}

// Round 7
// 135.256 us; speedup vs baseline: 2.8807x; 1.0530x over previous
//
#include <hip/hip_runtime.h>
#include <hip/hip_bf16.h>

#define HH 8
#define NNq 2048
#define EPSF 1e-5f
#define LOG2E 1.4426950408889634f

typedef __bf16 bf16x8 __attribute__((ext_vector_type(8)));
typedef float f32x4 __attribute__((ext_vector_type(4)));

typedef const __attribute__((address_space(1))) unsigned int* gas_t;
typedef __attribute__((address_space(3))) unsigned int* las_t;

__device__ __forceinline__ void async16(const void* g, void* l) {
  __builtin_amdgcn_global_load_lds((gas_t)g, (las_t)l, 16, 0, 0);
}
__device__ __forceinline__ void async4(const void* g, void* l) {
  __builtin_amdgcn_global_load_lds((gas_t)g, (las_t)l, 4, 0, 0);
}

__device__ __forceinline__ unsigned short f2bf(float f) {
  union { float f; unsigned int u; } a;
  a.f = f;
  unsigned int r = a.u + 0x7fffu + ((a.u >> 16) & 1u);
  return (unsigned short)(r >> 16);
}

// Chunk-XOR swizzle for bank-conflict-free ds_read_b128 fragments.
// Element (row, k) of a row-major [R x 512] bf16 matrix is stored at
// row*512 + swzk(row, k). 8-element (16B) chunks permute within 64-el groups.
__device__ __forceinline__ int swzk(int row, int k) {
  return (k & ~63) | ((((k >> 3) ^ row) & 7) << 3) | (k & 7);
}

// ---------------------------------------------------------------------------
// prep: blocks [0,1024) convert z fp32->bf16 (swizzled); [1024,1280) transpose
// weights fp32->bf16 [n][k] (swizzled); block 1280 zeroes k2max.
// ---------------------------------------------------------------------------
__global__ __launch_bounds__(256) void prep_kernel(
    const float* __restrict__ z, const float* __restrict__ W0,
    const float* __restrict__ W1, const float* __restrict__ W2,
    const float* __restrict__ W3, unsigned short* __restrict__ zb,
    unsigned short* __restrict__ Wt, unsigned int* __restrict__ k2max) {
  __shared__ float Tl[64][68];
  const int t = threadIdx.x;
  const int bx = blockIdx.x;
  if (bx < 1024) {
    const int i = (bx * 256 + t) * 8;
    const int row = i >> 9, k = i & 511;
    const float4 a = *(const float4*)&z[i];
    const float4 b = *(const float4*)&z[i + 4];
    union { unsigned short us[8]; uint4 v; } o;
    o.us[0] = f2bf(a.x); o.us[1] = f2bf(a.y); o.us[2] = f2bf(a.z); o.us[3] = f2bf(a.w);
    o.us[4] = f2bf(b.x); o.us[5] = f2bf(b.y); o.us[6] = f2bf(b.z); o.us[7] = f2bf(b.w);
    *(uint4*)&zb[(row << 9) | swzk(row, k)] = o.v;
  } else if (bx < 1280) {
    const int idx0 = bx - 1024;
    const int wsel = idx0 >> 6, rem = idx0 & 63;
    const int k0 = (rem >> 3) * 64, n0 = (rem & 7) * 64;
    const float* W = (wsel == 0) ? W0 : (wsel == 1) ? W1 : (wsel == 2) ? W2 : W3;
    unsigned short* dst = Wt + (size_t)wsel * 262144;
#pragma unroll
    for (int i = 0; i < 4; ++i) {
      const int idx = t + 256 * i;
      const int row = idx >> 4, cq = (idx & 15) * 4;
      *(float4*)&Tl[row][cq] = *(const float4*)&W[(size_t)(k0 + row) * 512 + n0 + cq];
    }
    __syncthreads();
#pragma unroll
    for (int i = 0; i < 4; ++i) {
      const int idx = t + 256 * i;
      const int nr = idx >> 4, kq = (idx & 15) * 4;
      ushort4 o;
      o.x = f2bf(Tl[kq + 0][nr]);
      o.y = f2bf(Tl[kq + 1][nr]);
      o.z = f2bf(Tl[kq + 2][nr]);
      o.w = f2bf(Tl[kq + 3][nr]);
      const int n = n0 + nr;
      *(ushort4*)&dst[(size_t)n * 512 + swzk(n, k0 + kq)] = o;
    }
  } else {
    k2max[t] = 0u;
  }
}

// ---------------------------------------------------------------------------
// Staged QKV projection + stats. 128 rows x 64 cols (one head) per block.
// BK=128 (4 K-iters), swizzle-aware conflict-free fragment reads.
// mode 0: Q bf16 [bh][n][64] (linear) + c1/dv/q2. mode 1: K swizzled attn
// tiles + k2/k2max. mode 2: V swizzled attn tiles (rows=dim, cols=key).
// ---------------------------------------------------------------------------
__global__ __launch_bounds__(256) void gemm_qkv(
    const unsigned short* __restrict__ A, const unsigned short* __restrict__ Wt3,
    const float* __restrict__ bq, const float* __restrict__ bk,
    const float* __restrict__ bvv, unsigned short* __restrict__ Qb,
    unsigned short* __restrict__ Ksw, unsigned short* __restrict__ Vsw,
    float* __restrict__ c1a, float* __restrict__ dva, float* __restrict__ k2a,
    float* __restrict__ q2a, unsigned int* __restrict__ k2max) {
  __shared__ __align__(16) unsigned short S[24576];  // As[128][128] | Bs[64][128]
  __shared__ float wmax[4];

  const int which = blockIdx.z;
  const unsigned short* Wt = Wt3 + (size_t)which * 262144;
  const float* bias = (which == 0) ? bq : (which == 1) ? bk : bvv;

  const int t = threadIdx.x;
  const int w = t >> 6, lane = t & 63, ln = lane & 15, quad = lane >> 4;
  const int r0 = blockIdx.x * 128, h = blockIdx.y;
  const int c0 = h * 64;
  const int b = r0 >> 11, n0 = r0 & 2047;
  const int bh = b * HH + h;

  f32x4 acc[2][4];
#pragma unroll
  for (int rf = 0; rf < 2; ++rf)
#pragma unroll
    for (int nt = 0; nt < 4; ++nt) acc[rf][nt] = (f32x4)(0.0f);

  const int lr = lane >> 4, lc = (lane & 15) * 8;  // 16 lanes per 256B row

  for (int k0 = 0; k0 < 512; k0 += 128) {
#pragma unroll
    for (int i = 0; i < 8; ++i)
      async16(A + (size_t)(r0 + w * 32 + i * 4 + lr) * 512 + k0 + lc,
              S + (w * 32 + i * 4) * 128);
#pragma unroll
    for (int i = 0; i < 4; ++i)
      async16(Wt + (size_t)(c0 + w * 16 + i * 4 + lr) * 512 + k0 + lc,
              S + 16384 + (w * 16 + i * 4) * 128);
    __syncthreads();
#pragma unroll
    for (int kk = 0; kk < 128; kk += 32) {
      const int cp = (kk >> 3) + quad;
      const int cs = ((cp & 8) | ((cp ^ (ln & 7)) & 7)) * 8;
      bf16x8 af[2];
#pragma unroll
      for (int rf = 0; rf < 2; ++rf)
        af[rf] = *(const bf16x8*)&S[(w * 32 + rf * 16 + ln) * 128 + cs];
#pragma unroll
      for (int nt = 0; nt < 4; ++nt) {
        const bf16x8 bf = *(const bf16x8*)&S[16384 + (nt * 16 + ln) * 128 + cs];
#pragma unroll
        for (int rf = 0; rf < 2; ++rf)
          acc[rf][nt] = __builtin_amdgcn_mfma_f32_16x16x32_bf16(af[rf], bf, acc[rf][nt], 0, 0, 0);
      }
    }
    __syncthreads();
  }

  float x[2][4][4];  // [rf][nt][r]
#pragma unroll
  for (int nt = 0; nt < 4; ++nt) {
    const float bv = bias[c0 + nt * 16 + ln];
#pragma unroll
    for (int rf = 0; rf < 2; ++rf)
#pragma unroll
      for (int r = 0; r < 4; ++r) x[rf][nt][r] = acc[rf][nt][r] + bv;
  }

  if (which == 0) {
#pragma unroll
    for (int rf = 0; rf < 2; ++rf)
#pragma unroll
      for (int r = 0; r < 4; ++r) {
        float s1 = x[rf][0][r] + x[rf][1][r] + x[rf][2][r] + x[rf][3][r];
#pragma unroll
        for (int off = 1; off < 16; off <<= 1) s1 += __shfl_xor(s1, off, 64);
        const float mu = s1 * (1.0f / 64.0f);
        float s2 = 0.0f, sa = 0.0f;
#pragma unroll
        for (int nt = 0; nt < 4; ++nt) {
          const float dx = x[rf][nt][r] - mu;
          s2 += dx * dx;
          sa += fabsf(dx);
        }
#pragma unroll
        for (int off = 1; off < 16; off <<= 1) {
          s2 += __shfl_xor(s2, off, 64);
          sa += __shfl_xor(sa, off, 64);
        }
        if (ln == 0) {
          const float sigma = sqrtf(s2 * (1.0f / 64.0f) + EPSF);
          const float nf = sa / (sigma + EPSF);
          const float dInv = 1.0f / (__expf(-nf) + 1.0f);
          const int row = bh * NNq + n0 + w * 32 + rf * 16 + quad * 4 + r;
          c1a[row] = (0.125f + 2.0f * dInv) * LOG2E;
          dva[row] = dInv * LOG2E;
          q2a[row] = s2 + 64.0f * mu * mu;
        }
      }
#pragma unroll
    for (int rf = 0; rf < 2; ++rf)
#pragma unroll
      for (int nt = 0; nt < 4; ++nt)
#pragma unroll
        for (int r = 0; r < 4; ++r)
          S[(w * 32 + rf * 16 + quad * 4 + r) * 72 + nt * 16 + ln] = f2bf(x[rf][nt][r]);
    __syncthreads();
#pragma unroll
    for (int i = 0; i < 4; ++i) {
      const int idx = t + 256 * i;
      const int q = idx >> 3, c = idx & 7;
      *(uint4*)&Qb[((size_t)bh * NNq + n0 + q) * 64 + c * 8] =
          *(const uint4*)&S[q * 72 + c * 8];
    }
  } else if (which == 1) {
    float mx = 0.0f;
#pragma unroll
    for (int rf = 0; rf < 2; ++rf)
#pragma unroll
      for (int r = 0; r < 4; ++r) {
        float s2 = 0.0f;
#pragma unroll
        for (int nt = 0; nt < 4; ++nt) s2 += x[rf][nt][r] * x[rf][nt][r];
#pragma unroll
        for (int off = 1; off < 16; off <<= 1) s2 += __shfl_xor(s2, off, 64);
        if (ln == 0) k2a[bh * NNq + n0 + w * 32 + rf * 16 + quad * 4 + r] = s2;
        mx = fmaxf(mx, s2);
      }
#pragma unroll
    for (int off = 16; off < 64; off <<= 1) mx = fmaxf(mx, __shfl_xor(mx, off, 64));
    if (lane == 0) wmax[w] = mx;
#pragma unroll
    for (int rf = 0; rf < 2; ++rf)
#pragma unroll
      for (int nt = 0; nt < 4; ++nt) {
        const int c = nt * 2 + (ln >> 3);
#pragma unroll
        for (int r = 0; r < 4; ++r) {
          const int key = w * 32 + rf * 16 + quad * 4 + r;
          const int klo = key & 63;
          S[(key >> 6) * 4096 + klo * 64 + ((c ^ (klo & 7)) * 8) + (ln & 7)] =
              f2bf(x[rf][nt][r]);
        }
      }
    __syncthreads();
    if (t == 0) {
      const float m = fmaxf(fmaxf(wmax[0], wmax[1]), fmaxf(wmax[2], wmax[3]));
      atomicMax(&k2max[bh * 16], __float_as_uint(m));
    }
    unsigned short* dst = Ksw + ((size_t)bh * 32 + (n0 >> 6)) * 4096;
#pragma unroll
    for (int i = 0; i < 4; ++i) {
      const int idx = t + 256 * i;
      *(uint4*)&dst[idx * 8] = *(const uint4*)&S[idx * 8];
    }
  } else {
#pragma unroll
    for (int rf = 0; rf < 2; ++rf)
#pragma unroll
      for (int nt = 0; nt < 4; ++nt) {
        const int d = nt * 16 + ln;
#pragma unroll
        for (int r = 0; r < 4; ++r) {
          const int key = w * 32 + rf * 16 + quad * 4 + r;
          const int klo = key & 63;
          S[d * 128 + (key >> 6) * 64 + (((klo >> 3) ^ (d & 7)) * 8) + (klo & 7)] =
              f2bf(x[rf][nt][r]);
        }
      }
    __syncthreads();
    unsigned short* dst = Vsw + ((size_t)bh * 32 + (n0 >> 6)) * 4096;
#pragma unroll
    for (int i = 0; i < 4; ++i) {
      const int g = t + 256 * i;
      const int tile = g >> 9, d = (g >> 3) & 63, j8 = (g & 7) * 8;
      *(uint4*)&dst[tile * 4096 + d * 64 + j8] =
          *(const uint4*)&S[d * 128 + tile * 64 + j8];
    }
  }
}

// ---------------------------------------------------------------------------
// Flash attention, 512 threads = 8 waves: waves 0-3 keys [0,1024),
// waves 4-7 keys [1024,2048). Fixed-bound softmax; k2 preloaded per half;
// P packed with native __float22bfloat162_rn; swizzled attnb output.
// ---------------------------------------------------------------------------
__global__ __launch_bounds__(512) void attn_kernel(
    const unsigned short* __restrict__ Qb, const unsigned short* __restrict__ Ksw,
    const unsigned short* __restrict__ Vsw, const float* __restrict__ c1a,
    const float* __restrict__ dva, const float* __restrict__ k2a,
    const float* __restrict__ q2a, const unsigned int* __restrict__ k2maxu,
    unsigned short* __restrict__ attnb) {
  // [0,32768): per-half K(8K)+V(8K); aliased as fp32 O partials at the end.
  // [32768,51200): per-half Ps [64][72] bf16; aliased as L storage.
  // [51200,59392): per-half k2 (1024 floats each).
  __shared__ __align__(16) char smem[59392];

  const int t = threadIdx.x;
  const int w8 = t >> 6, lane = t & 63, ln = lane & 15, quad = lane >> 4;
  const int half = w8 >> 2, wl = w8 & 3;
  const int qt = blockIdx.x, bh = blockIdx.y;
  const int b = bh >> 3, h = bh & 7;
  const int q0 = qt * 64;
  const int rowbase = bh * NNq;

  unsigned short* Kt = (unsigned short*)(smem + half * 16384);
  unsigned short* Vt = (unsigned short*)(smem + half * 16384 + 8192);
  unsigned short* Ps = (unsigned short*)(smem + 32768 + half * 9216);
  float* k2h = (float*)(smem + 51200 + half * 4096);

  // Preload this half's k2 (1024 floats) once.
  const float* k2g = k2a + rowbase + half * 1024;
#pragma unroll
  for (int i = 0; i < 4; ++i)
    async4(k2g + wl * 256 + i * 64 + lane, k2h + wl * 256 + i * 64);

  // Q fragment: lane ln holds query q0 + wl*16 + ln (B-operand for S^T).
  const int qg = q0 + wl * 16 + ln;
  const unsigned short* qrow = Qb + ((size_t)rowbase + qg) * 64;
  const bf16x8 aq0 = *(const bf16x8*)(qrow + quad * 8);
  const bf16x8 aq1 = *(const bf16x8*)(qrow + 32 + quad * 8);

  const float k2m = __uint_as_float(k2maxu[bh * 16]);
  const float c1q = c1a[rowbase + qg];
  const float dvq = dva[rowbase + qg];
  const float Mqq = c1q * sqrtf(q2a[rowbase + qg] * k2m);
  float L = 0.0f;
  f32x4 O[4];
#pragma unroll
  for (int nt = 0; nt < 4; ++nt) O[nt] = (f32x4)(0.0f);

  const unsigned short* Kg = Ksw + (size_t)bh * 32 * 4096;
  const unsigned short* Vg = Vsw + (size_t)bh * 32 * 4096;
  const int sw = quad ^ (ln & 7);
  const int sw1 = (4 + quad) ^ (ln & 7);

  for (int kt = 0; kt < 16; ++kt) {
    {
      const size_t tb = (size_t)(half * 16 + kt) * 4096 + wl * 1024;
      async16(Kg + tb + lane * 8, Kt + wl * 1024);
      async16(Kg + tb + 512 + lane * 8, Kt + wl * 1024 + 512);
      async16(Vg + tb + lane * 8, Vt + wl * 1024);
      async16(Vg + tb + 512 + lane * 8, Vt + wl * 1024 + 512);
    }
    __syncthreads();

    // ---- S^T = K Q^T ----
    f32x4 s[4];
#pragma unroll
    for (int nt = 0; nt < 4; ++nt) {
      const unsigned short* kb = Kt + (nt * 16 + ln) * 64;
      const bf16x8 b0 = *(const bf16x8*)(kb + sw * 8);
      const bf16x8 b1 = *(const bf16x8*)(kb + sw1 * 8);
      f32x4 a = (f32x4)(0.0f);
      a = __builtin_amdgcn_mfma_f32_16x16x32_bf16(b0, aq0, a, 0, 0, 0);
      a = __builtin_amdgcn_mfma_f32_16x16x32_bf16(b1, aq1, a, 0, 0, 0);
      s[nt] = a;
    }

    // ---- softmax (scalar per lane) + packed P^T write ----
#pragma unroll
    for (int nt = 0; nt < 4; ++nt) {
      const f32x4 k2v = *(const f32x4*)&k2h[kt * 64 + nt * 16 + quad * 4];
      const float p0 = __builtin_amdgcn_exp2f(c1q * s[nt][0] - dvq * k2v[0] - Mqq);
      const float p1 = __builtin_amdgcn_exp2f(c1q * s[nt][1] - dvq * k2v[1] - Mqq);
      const float p2 = __builtin_amdgcn_exp2f(c1q * s[nt][2] - dvq * k2v[2] - Mqq);
      const float p3 = __builtin_amdgcn_exp2f(c1q * s[nt][3] - dvq * k2v[3] - Mqq);
      L += (p0 + p1) + (p2 + p3);
      union { __hip_bfloat162 h; unsigned int u; } c01, c23;
      c01.h = __float22bfloat162_rn(make_float2(p0, p1));
      c23.h = __float22bfloat162_rn(make_float2(p2, p3));
      uint2 pu; pu.x = c01.u; pu.y = c23.u;
      *(uint2*)&Ps[(wl * 16 + ln) * 72 + nt * 16 + quad * 4] = pu;
    }
    const unsigned short* pr = Ps + (wl * 16 + ln) * 72;
    const bf16x8 pa0 = *(const bf16x8*)(pr + quad * 8);
    const bf16x8 pa1 = *(const bf16x8*)(pr + 32 + quad * 8);

    // ---- O += P V ----
#pragma unroll
    for (int nt = 0; nt < 4; ++nt) {
      const unsigned short* vb = Vt + (nt * 16 + ln) * 64;
      const bf16x8 vb0 = *(const bf16x8*)(vb + sw * 8);
      const bf16x8 vb1 = *(const bf16x8*)(vb + sw1 * 8);
      O[nt] = __builtin_amdgcn_mfma_f32_16x16x32_bf16(pa0, vb0, O[nt], 0, 0, 0);
      O[nt] = __builtin_amdgcn_mfma_f32_16x16x32_bf16(pa1, vb1, O[nt], 0, 0, 0);
    }
    __syncthreads();
  }

  // ---- L: sum across quads (lane holds query wl*16+ln) ----
  L += __shfl_xor(L, 16, 64);
  L += __shfl_xor(L, 32, 64);

  // ---- stage partial O (fp32, aliases K/V) and L (aliases Ps) ----
  float* Ost = (float*)(smem + half * 16384);
  float* Lst = (float*)(smem + 32768 + half * 9216);
#pragma unroll
  for (int nt = 0; nt < 4; ++nt)
#pragma unroll
    for (int r = 0; r < 4; ++r)
      Ost[(wl * 16 + quad * 4 + r) * 64 + nt * 16 + ln] = O[nt][r];
  if (quad == 0) Lst[wl * 16 + ln] = L;
  __syncthreads();

  // ---- combine halves, normalize, write bf16 swizzled [B,N,DIM] ----
  const float* O0 = (const float*)smem;
  const float* O1 = (const float*)(smem + 16384);
  const float* L0 = (const float*)(smem + 32768);
  const float* L1 = (const float*)(smem + 32768 + 9216);
  const int q = t >> 3, c8 = (t & 7) * 8;
  const float inv = 1.0f / (L0[q] + L1[q]);
  const int base = q * 64 + c8;
  float4 a0 = *(const float4*)&O0[base];
  float4 a1 = *(const float4*)&O0[base + 4];
  const float4 b0 = *(const float4*)&O1[base];
  const float4 b1 = *(const float4*)&O1[base + 4];
  union { unsigned short us[8]; uint4 v; } ov;
  ov.us[0] = f2bf((a0.x + b0.x) * inv);
  ov.us[1] = f2bf((a0.y + b0.y) * inv);
  ov.us[2] = f2bf((a0.z + b0.z) * inv);
  ov.us[3] = f2bf((a0.w + b0.w) * inv);
  ov.us[4] = f2bf((a1.x + b1.x) * inv);
  ov.us[5] = f2bf((a1.y + b1.y) * inv);
  ov.us[6] = f2bf((a1.z + b1.z) * inv);
  ov.us[7] = f2bf((a1.w + b1.w) * inv);
  const int nrow = q0 + q;
  *(uint4*)&attnb[((size_t)(b * NNq + nrow)) * 512 + swzk(nrow, h * 64 + c8)] = ov.v;
}

// ---------------------------------------------------------------------------
// Staged out projection: out fp32 = attnb bf16 [4096,512] @ WoT + bo.
// BK=128, swizzle-aware reads, Tl aliased onto S. grid (64,8).
// ---------------------------------------------------------------------------
__global__ __launch_bounds__(256) void gemm_out(
    const unsigned short* __restrict__ A, const unsigned short* __restrict__ Wt,
    const float* __restrict__ bias, float* __restrict__ of) {
  __shared__ __align__(16) char sbuf[32768];  // As[64][128] | Bs[64][128]
  unsigned short* S = (unsigned short*)sbuf;
  float (*Tl)[68] = (float(*)[68])sbuf;  // aliased epilogue staging

  const int t = threadIdx.x;
  const int w = t >> 6, lane = t & 63, ln = lane & 15, quad = lane >> 4;
  const int r0 = blockIdx.x * 64, c0 = blockIdx.y * 64;
  const int lr = lane >> 4, lc = (lane & 15) * 8;

  f32x4 acc[4];
#pragma unroll
  for (int nt = 0; nt < 4; ++nt) acc[nt] = (f32x4)(0.0f);

  for (int k0 = 0; k0 < 512; k0 += 128) {
#pragma unroll
    for (int i = 0; i < 4; ++i) {
      async16(A + (size_t)(r0 + w * 16 + i * 4 + lr) * 512 + k0 + lc,
              S + (w * 16 + i * 4) * 128);
      async16(Wt + (size_t)(c0 + w * 16 + i * 4 + lr) * 512 + k0 + lc,
              S + 8192 + (w * 16 + i * 4) * 128);
    }
    __syncthreads();
#pragma unroll
    for (int kk = 0; kk < 128; kk += 32) {
      const int cp = (kk >> 3) + quad;
      const int cs = ((cp & 8) | ((cp ^ (ln & 7)) & 7)) * 8;
      const bf16x8 af = *(const bf16x8*)&S[(w * 16 + ln) * 128 + cs];
#pragma unroll
      for (int nt = 0; nt < 4; ++nt) {
        const bf16x8 bf = *(const bf16x8*)&S[8192 + (nt * 16 + ln) * 128 + cs];
        acc[nt] = __builtin_amdgcn_mfma_f32_16x16x32_bf16(af, bf, acc[nt], 0, 0, 0);
      }
    }
    __syncthreads();
  }
#pragma unroll
  for (int nt = 0; nt < 4; ++nt) {
    const float bv = bias[c0 + nt * 16 + ln];
#pragma unroll
    for (int r = 0; r < 4; ++r)
      Tl[w * 16 + quad * 4 + r][nt * 16 + ln] = acc[nt][r] + bv;
  }
  __syncthreads();
#pragma unroll
  for (int i = 0; i < 4; ++i) {
    const int idx = t + 256 * i;
    const int row = idx >> 4, c4 = (idx & 15) * 4;
    *(float4*)&of[(size_t)(r0 + row) * 512 + c0 + c4] = *(const float4*)&Tl[row][c4];
  }
}

// ---------------------------------------------------------------------------
extern "C" void kernel_launch(void* const* d_in, const int* in_sizes, int n_in,
                              void* d_out, int out_size, void* d_ws,
                              size_t ws_size, hipStream_t stream) {
  const float* z = (const float*)d_in[0];
  const float* Wq = (const float*)d_in[1];
  const float* bq = (const float*)d_in[2];
  const float* Wk = (const float*)d_in[3];
  const float* bk = (const float*)d_in[4];
  const float* Wv = (const float*)d_in[5];
  const float* bv = (const float*)d_in[6];
  const float* Wo = (const float*)d_in[7];
  const float* bo = (const float*)d_in[8];
  float* out = (float*)d_out;

  char* ws = (char*)d_ws;
  unsigned short* zb = (unsigned short*)(ws);                // 4 MiB
  unsigned short* Wt = (unsigned short*)(ws + 4194304);      // 2 MiB
  unsigned short* Qb = (unsigned short*)(ws + 6291456);      // 4 MiB
  unsigned short* Ksw = (unsigned short*)(ws + 10485760);    // 4 MiB
  unsigned short* Vsw = (unsigned short*)(ws + 14680064);    // 4 MiB
  float* c1 = (float*)(ws + 18874368);                       // 128 KiB each
  float* dv = (float*)(ws + 19005440);
  float* k2 = (float*)(ws + 19136512);
  float* q2 = (float*)(ws + 19267584);
  unsigned short* attnb = (unsigned short*)(ws + 19398656);  // 4 MiB
  unsigned int* k2max = (unsigned int*)(ws + 23592960);      // 1 KiB

  hipLaunchKernelGGL(prep_kernel, dim3(1281), dim3(256), 0, stream, z, Wq, Wk,
                     Wv, Wo, zb, Wt, k2max);
  hipLaunchKernelGGL(gemm_qkv, dim3(32, 8, 3), dim3(256), 0, stream, zb, Wt,
                     bq, bk, bv, Qb, Ksw, Vsw, c1, dv, k2, q2, k2max);
  hipLaunchKernelGGL(attn_kernel, dim3(32, 16), dim3(512), 0, stream, Qb, Ksw,
                     Vsw, c1, dv, k2, q2, k2max, attnb);
  hipLaunchKernelGGL(gemm_out, dim3(64, 8), dim3(256), 0, stream, attnb,
                     Wt + 786432, bo, out);
}